// Round 8
// baseline (201.190 us; speedup 1.0000x reference)
//
#include <hip/hip_runtime.h>
// R8: kill the LDS-read bottleneck. B operands served from L2-resident global
// (pre-transposed Wt/Bt2; H already [k][n]) with register group-prefetch;
// LDS stages A only. 1 ds_read_b128 + 1 global b128 per 16 FMAs.

#define NEGINF (-1e30f)

__device__ inline float waveRedSum(float v){
  #pragma unroll
  for (int o = 32; o > 0; o >>= 1) v += __shfl_down(v, o, 64);
  return v;
}
__device__ inline float waveRedMax(float v){
  #pragma unroll
  for (int o = 32; o > 0; o >>= 1) v = fmaxf(v, __shfl_down(v, o, 64));
  return v;
}
__device__ inline float4 f4z(){ return make_float4(0.f,0.f,0.f,0.f); }

// ---- k0a: Wt[k][c] = W[c][k], k<768, c<320 (zero-pad c>=300). LDS-tiled 32x32.
__global__ __launch_bounds__(256) void k0a_wt(const float* __restrict__ W,
                                              float* __restrict__ Wt){
  __shared__ float ld[32][33];
  const int c0 = blockIdx.x * 32;
  const int k0 = blockIdx.y * 32;
  const int t  = threadIdx.x;
  #pragma unroll
  for (int r = 0; r < 4; r++){
    int c = c0 + r*8 + (t >> 5), k = k0 + (t & 31);
    ld[r*8 + (t >> 5)][t & 31] = (c < 300) ? W[(size_t)c * 768 + k] : 0.f;
  }
  __syncthreads();
  #pragma unroll
  for (int r = 0; r < 4; r++){
    int kL = r*8 + (t >> 5), cL = t & 31;
    Wt[(size_t)(k0 + kL) * 320 + c0 + cL] = ld[cL][kL];
  }
}

// ---- k0b: Bt2[k][n] = k<300 ? (n<64 ? a1w[n][k] : a1w[n-64][300+k]) : 0
__global__ __launch_bounds__(128) void k0b_bt(const float* __restrict__ a1w,
                                              float* __restrict__ Bt2){
  const int k = blockIdx.x, n = threadIdx.x;
  float v = 0.f;
  if (k < 300) v = (n < 64) ? a1w[(size_t)n * 600 + k] : a1w[(size_t)(n - 64) * 600 + 300 + k];
  Bt2[(size_t)k * 128 + n] = v;
}

#define FMA16(a4, b4) { \
  acc0.x += a4.x*b4.x; acc0.y += a4.x*b4.y; acc0.z += a4.x*b4.z; acc0.w += a4.x*b4.w; \
  acc1.x += a4.y*b4.x; acc1.y += a4.y*b4.y; acc1.z += a4.y*b4.z; acc1.w += a4.y*b4.w; \
  acc2.x += a4.z*b4.x; acc2.y += a4.z*b4.y; acc2.z += a4.z*b4.z; acc2.w += a4.z*b4.w; \
  acc3.x += a4.w*b4.x; acc3.y += a4.w*b4.y; acc3.z += a4.w*b4.z; acc3.w += a4.w*b4.w; }

// ---------------- K1: H = feat @ Wt + Wb  [4096 x 300], K=768 ----------------
// 128 thr, tile 32Mx64N, 4x4 acc. A via LDS (dbuf), B from L2 (group prefetch).
__global__ __launch_bounds__(128) void k1_h(const float* __restrict__ A,
                                            const float* __restrict__ Wt,
                                            const float* __restrict__ Wb,
                                            float* __restrict__ H){
  __shared__ float At[2][32][36];
  const int fid = blockIdx.x;
  const int wl  = (fid & 7) * 80 + (fid >> 3);
  const int x   = wl % 5, y = wl / 5;
  const int c0 = x * 64, m0 = y * 32;
  const int t  = threadIdx.x;
  const int tr4 = (t >> 4) * 4;
  const int tc4 = (t & 15) * 4;
  const int sr  = t >> 3;
  const int sc  = (t & 7) * 4;
  const int col = c0 + tc4;                 // < 320 (Wt padded)
  const float* Bg = Wt + col;
  float4 ra0, ra1;
#define K1_LD(kt) { \
    ra0 = *(const float4*)&A[(size_t)(m0 + sr     ) * 768 + (kt) + sc]; \
    ra1 = *(const float4*)&A[(size_t)(m0 + 16 + sr) * 768 + (kt) + sc]; }
  float4 bA[8], bB[8];
  #pragma unroll
  for (int u = 0; u < 8; u++) bA[u] = *(const float4*)&Bg[(size_t)u * 320];
  K1_LD(0)
  float4 acc0 = f4z(), acc1 = f4z(), acc2 = f4z(), acc3 = f4z();
  int p = 0;
#define K1_GRP(BC, BN, G) { \
    const int sn = sbase + (G) + 1; \
    if (sn < 96){ _Pragma("unroll") \
      for (int u = 0; u < 8; u++) BN[u] = *(const float4*)&Bg[(size_t)(sn*8 + u) * 320]; } \
    _Pragma("unroll") \
    for (int u = 0; u < 8; u++){ \
      const float4 a4 = *(const float4*)&At[p][(G)*8 + u][tr4]; \
      FMA16(a4, BC[u]) } }
  for (int kt = 0; kt < 768; kt += 32){
    #pragma unroll
    for (int i = 0; i < 4; i++){
      At[p][sc+i][sr     ] = (&ra0.x)[i];
      At[p][sc+i][16 + sr] = (&ra1.x)[i];
    }
    __syncthreads();
    if (kt + 32 < 768) K1_LD(kt + 32)
    const int sbase = kt >> 3;
    K1_GRP(bA, bB, 0)
    K1_GRP(bB, bA, 1)
    K1_GRP(bA, bB, 2)
    K1_GRP(bB, bA, 3)
    p ^= 1;
  }
#undef K1_GRP
#undef K1_LD
  if (col < 300){
    const float4 bi = *(const float4*)&Wb[col];
    float4 o;
    o = make_float4(acc0.x+bi.x, acc0.y+bi.y, acc0.z+bi.z, acc0.w+bi.w);
    *(float4*)&H[(size_t)(m0 + tr4 + 0) * 300 + col] = o;
    o = make_float4(acc1.x+bi.x, acc1.y+bi.y, acc1.z+bi.z, acc1.w+bi.w);
    *(float4*)&H[(size_t)(m0 + tr4 + 1) * 300 + col] = o;
    o = make_float4(acc2.x+bi.x, acc2.y+bi.y, acc2.z+bi.z, acc2.w+bi.w);
    *(float4*)&H[(size_t)(m0 + tr4 + 2) * 300 + col] = o;
    o = make_float4(acc3.x+bi.x, acc3.y+bi.y, acc3.z+bi.z, acc3.w+bi.w);
    *(float4*)&H[(size_t)(m0 + tr4 + 3) * 300 + col] = o;
  }
}

// ---------------- K2: S = H @ Bt2 (+a1b on cols<64)  [4096 x 128], K=300 (pad 320)
__global__ __launch_bounds__(128) void k2_s(const float* __restrict__ Hm,
                                            const float* __restrict__ Bt2,
                                            const float* __restrict__ a1b,
                                            float* __restrict__ S){
  __shared__ float At[2][32][36];
  const int c0 = blockIdx.x * 64;
  const int m0 = blockIdx.y * 32;
  const int t  = threadIdx.x;
  const int tr4 = (t >> 4) * 4;
  const int tc4 = (t & 15) * 4;
  const int sr  = t >> 3;
  const int sc  = (t & 7) * 4;
  const int col = c0 + tc4;                 // < 128
  const float* Bg = Bt2 + col;
  float4 ra0, ra1;
#define K2_LD(kt) { const int kx = (kt) + sc; \
    if (kx < 300){ \
      ra0 = *(const float4*)&Hm[(size_t)(m0 + sr     ) * 300 + kx]; \
      ra1 = *(const float4*)&Hm[(size_t)(m0 + 16 + sr) * 300 + kx]; \
    } else { ra0 = f4z(); ra1 = f4z(); } }
  float4 bA[8], bB[8];
  #pragma unroll
  for (int u = 0; u < 8; u++) bA[u] = *(const float4*)&Bg[(size_t)u * 128];
  K2_LD(0)
  float4 acc0 = f4z(), acc1 = f4z(), acc2 = f4z(), acc3 = f4z();
  int p = 0;
#define K2_GRP(BC, BN, G) { \
    const int sn = sbase + (G) + 1; \
    if (sn < 40){ _Pragma("unroll") \
      for (int u = 0; u < 8; u++) BN[u] = *(const float4*)&Bg[(size_t)(sn*8 + u) * 128]; } \
    _Pragma("unroll") \
    for (int u = 0; u < 8; u++){ \
      const float4 a4 = *(const float4*)&At[p][(G)*8 + u][tr4]; \
      FMA16(a4, BC[u]) } }
  for (int kt = 0; kt < 320; kt += 32){
    #pragma unroll
    for (int i = 0; i < 4; i++){
      At[p][sc+i][sr     ] = (&ra0.x)[i];
      At[p][sc+i][16 + sr] = (&ra1.x)[i];
    }
    __syncthreads();
    if (kt + 32 < 320) K2_LD(kt + 32)
    const int sbase = kt >> 3;
    K2_GRP(bA, bB, 0)
    K2_GRP(bB, bA, 1)
    K2_GRP(bA, bB, 2)
    K2_GRP(bB, bA, 3)
    p ^= 1;
  }
#undef K2_GRP
#undef K2_LD
  float4 bi = f4z();
  if (col < 64) bi = *(const float4*)&a1b[col];
  float4 o;
  o = make_float4(acc0.x+bi.x, acc0.y+bi.y, acc0.z+bi.z, acc0.w+bi.w);
  *(float4*)&S[(size_t)(m0 + tr4 + 0) * 128 + col] = o;
  o = make_float4(acc1.x+bi.x, acc1.y+bi.y, acc1.z+bi.z, acc1.w+bi.w);
  *(float4*)&S[(size_t)(m0 + tr4 + 1) * 128 + col] = o;
  o = make_float4(acc2.x+bi.x, acc2.y+bi.y, acc2.z+bi.z, acc2.w+bi.w);
  *(float4*)&S[(size_t)(m0 + tr4 + 2) * 128 + col] = o;
  o = make_float4(acc3.x+bi.x, acc3.y+bi.y, acc3.z+bi.z, acc3.w+bi.w);
  *(float4*)&S[(size_t)(m0 + tr4 + 3) * 128 + col] = o;
}

// ---------------- K3: logits + mask + per-block (max, sum-exp) ----------------------
__global__ __launch_bounds__(256) void k3_logits(const float* __restrict__ S,
                                                 const float* __restrict__ adj,
                                                 const float* __restrict__ a2w,
                                                 const float* __restrict__ a2b,
                                                 float* __restrict__ L,
                                                 float* __restrict__ bm,
                                                 float* __restrict__ bs){
  __shared__ float si_s[32][64];
  __shared__ float sj_s[64][64];
  __shared__ float w_s[64];
  __shared__ float redm[4];
  __shared__ float reds[4];
  __shared__ float smax;
  const int b  = blockIdx.z;
  const int i0 = blockIdx.y * 32;
  const int j0 = blockIdx.x * 64;
  const int t  = threadIdx.x;
  if (t < 16) *(float4*)&w_s[t*4] = *(const float4*)&a2w[t*4];
  #pragma unroll
  for (int q = 0; q < 2; q++){
    int c = t + q*256; int r = c >> 4, c4 = c & 15;
    *(float4*)&si_s[r][c4*4] = *(const float4*)&S[(size_t)(b*512 + i0 + r)*128 + c4*4];
  }
  #pragma unroll
  for (int q = 0; q < 4; q++){
    int c = t + q*256; int r = c >> 4, c4 = c & 15;
    int c4s = c4 ^ (r & 7);
    *(float4*)&sj_s[r][c4s*4] = *(const float4*)&S[(size_t)(b*512 + j0 + r)*128 + 64 + c4*4];
  }
  __syncthreads();
  const int j = t & 63, iq = t >> 6;
  const float a2bv = a2b[0];
  float4 acc[8];
  #pragma unroll
  for (int ii = 0; ii < 8; ii++) acc[ii] = f4z();
  #pragma unroll
  for (int k4 = 0; k4 < 16; k4++){
    float4 sj4 = *(float4*)&sj_s[j][(k4 ^ (j & 7))*4];
    float4 w4  = *(float4*)&w_s[k4*4];
    #pragma unroll
    for (int ii = 0; ii < 8; ii++){
      int i = ii*4 + iq;
      float4 si4 = *(float4*)&si_s[i][k4*4];
      acc[ii].x += fmaxf(si4.x + sj4.x, 0.f) * w4.x;
      acc[ii].y += fmaxf(si4.y + sj4.y, 0.f) * w4.y;
      acc[ii].z += fmaxf(si4.z + sj4.z, 0.f) * w4.z;
      acc[ii].w += fmaxf(si4.w + sj4.w, 0.f) * w4.w;
    }
  }
  float l_arr[8];
  float locmax = -3e38f;
  #pragma unroll
  for (int ii = 0; ii < 8; ii++){
    int i = ii*4 + iq;
    float e = ((acc[ii].x + acc[ii].y) + (acc[ii].z + acc[ii].w)) + a2bv;
    e = (e >= 0.f) ? e : 0.01f * e;
    size_t idx = (size_t)(b*512 + i0 + i)*512 + j0 + j;
    float l = (adj[idx] != 0.f) ? e : NEGINF;
    l_arr[ii] = l;
    L[idx] = l;
    locmax = fmaxf(locmax, l);
  }
  float m = waveRedMax(locmax);
  if ((t & 63) == 0) redm[t >> 6] = m;
  __syncthreads();
  if (t == 0) smax = fmaxf(fmaxf(redm[0], redm[1]), fmaxf(redm[2], redm[3]));
  __syncthreads();
  const float mb = smax;
  float s = 0.f;
  #pragma unroll
  for (int ii = 0; ii < 8; ii++) s += __expf(l_arr[ii] - mb);
  s = waveRedSum(s);
  if ((t & 63) == 0) reds[t >> 6] = s;
  __syncthreads();
  if (t == 0){
    const int bid = (blockIdx.z * 16 + blockIdx.y) * 8 + blockIdx.x;
    bm[bid] = mb;
    bs[bid] = (reds[0] + reds[1]) + (reds[2] + reds[3]);
  }
}

// ---------------- K6: combine per-block (m,s) -> per-batch (maxg, sums) -------------
__global__ __launch_bounds__(128) void k6_red(const float* __restrict__ bm,
                                              const float* __restrict__ bs,
                                              float* __restrict__ sums,
                                              float* __restrict__ maxg){
  const int b = blockIdx.x, t = threadIdx.x;
  const float m = bm[b*128 + t];
  float mm = waveRedMax(m);
  __shared__ float r2m[2];
  __shared__ float mgs;
  if ((t & 63) == 0) r2m[t >> 6] = mm;
  __syncthreads();
  if (t == 0) mgs = fmaxf(r2m[0], r2m[1]);
  __syncthreads();
  const float mg = mgs;
  float v = bs[b*128 + t] * __expf(m - mg);
  v = waveRedSum(v);
  __shared__ float r2s[2];
  if ((t & 63) == 0) r2s[t >> 6] = v;
  __syncthreads();
  if (t == 0){ sums[b] = r2s[0] + r2s[1]; maxg[b] = mg; }
}

// ---------------- K7: out = (exp(L-maxg) @ H) / sums; per-batch [512x300], K=512 ----
// A (L, exp'd) via LDS dbuf; B = H rows direct from L2 (one batch per XCD).
__global__ __launch_bounds__(128) void k7_out(const float* __restrict__ Lr,
                                              const float* __restrict__ Hm,
                                              const float* __restrict__ sums,
                                              const float* __restrict__ maxg,
                                              float* __restrict__ out){
  __shared__ float At[2][32][36];
  const int fid = blockIdx.x;
  const int wl  = (fid & 7) * 80 + (fid >> 3);
  const int bz  = wl / 80;
  const int rem = wl % 80;
  const int y   = rem / 5, x = rem % 5;
  const int c0 = x * 64, m0 = y * 32;
  const int t  = threadIdx.x;
  const int tr4 = (t >> 4) * 4;
  const int tc4 = (t & 15) * 4;
  const int sr  = t >> 3;
  const int sc  = (t & 7) * 4;
  const int col = c0 + tc4;
  const bool valid = (col < 300);
  const float mx = maxg[bz];
  const size_t Lb = (size_t)bz * 262144;
  const float* Bg = Hm + (size_t)bz * 153600 + col;
  float4 ra0, ra1;
#define K7_LD(kt) { \
    ra0 = *(const float4*)&Lr[Lb + (size_t)(m0 + sr     ) * 512 + (kt) + sc]; \
    ra1 = *(const float4*)&Lr[Lb + (size_t)(m0 + 16 + sr) * 512 + (kt) + sc]; }
  float4 bA[8], bB[8];
  #pragma unroll
  for (int u = 0; u < 8; u++) bA[u] = f4z();
  if (valid){
    #pragma unroll
    for (int u = 0; u < 8; u++) bA[u] = *(const float4*)&Bg[(size_t)u * 300];
  }
  K7_LD(0)
  float4 acc0 = f4z(), acc1 = f4z(), acc2 = f4z(), acc3 = f4z();
  int p = 0;
#define K7_GRP(BC, BN, G) { \
    const int sn = sbase + (G) + 1; \
    if (valid && sn < 64){ _Pragma("unroll") \
      for (int u = 0; u < 8; u++) BN[u] = *(const float4*)&Bg[(size_t)(sn*8 + u) * 300]; } \
    _Pragma("unroll") \
    for (int u = 0; u < 8; u++){ \
      const float4 a4 = *(const float4*)&At[p][(G)*8 + u][tr4]; \
      FMA16(a4, BC[u]) } }
  for (int kt = 0; kt < 512; kt += 32){
    #pragma unroll
    for (int i = 0; i < 4; i++){
      At[p][sc+i][sr     ] = __expf((&ra0.x)[i] - mx);
      At[p][sc+i][16 + sr] = __expf((&ra1.x)[i] - mx);
    }
    __syncthreads();
    if (kt + 32 < 512) K7_LD(kt + 32)
    const int sbase = kt >> 3;
    K7_GRP(bA, bB, 0)
    K7_GRP(bB, bA, 1)
    K7_GRP(bA, bB, 2)
    K7_GRP(bB, bA, 3)
    p ^= 1;
  }
#undef K7_GRP
#undef K7_LD
  if (valid){
    const float invs = 1.0f / sums[bz];
    const size_t Hb = (size_t)bz * 512;
    float4 o;
    o = make_float4(acc0.x*invs, acc0.y*invs, acc0.z*invs, acc0.w*invs);
    *(float4*)&out[(Hb + m0 + tr4 + 0) * 300 + col] = o;
    o = make_float4(acc1.x*invs, acc1.y*invs, acc1.z*invs, acc1.w*invs);
    *(float4*)&out[(Hb + m0 + tr4 + 1) * 300 + col] = o;
    o = make_float4(acc2.x*invs, acc2.y*invs, acc2.z*invs, acc2.w*invs);
    *(float4*)&out[(Hb + m0 + tr4 + 2) * 300 + col] = o;
    o = make_float4(acc3.x*invs, acc3.y*invs, acc3.z*invs, acc3.w*invs);
    *(float4*)&out[(Hb + m0 + tr4 + 3) * 300 + col] = o;
  }
}

extern "C" void kernel_launch(void* const* d_in, const int* in_sizes, int n_in,
                              void* d_out, int out_size, void* d_ws, size_t ws_size,
                              hipStream_t stream){
  const float* adj  = (const float*)d_in[0];
  const float* feat = (const float*)d_in[1];
  const float* Ww   = (const float*)d_in[2];
  const float* Wb   = (const float*)d_in[3];
  const float* a1w  = (const float*)d_in[4];
  const float* a1b  = (const float*)d_in[5];
  const float* a2w  = (const float*)d_in[6];
  const float* a2b  = (const float*)d_in[7];
  float* out = (float*)d_out;
  char* ws = (char*)d_ws;

  float* H    = (float*)(ws + 0);            // 4,915,200 B
  float* S    = (float*)(ws + 4915200);      // 2,097,152 B
  float* L    = (float*)(ws + 7012352);      // 8,388,608 B
  float* Wt   = (float*)(ws + 15400960);     // 983,040 B (768x320)
  float* Bt2  = (float*)(ws + 16384000);     // 163,840 B (320x128)
  float* bm   = (float*)(ws + 16547840);     // 4,096 B
  float* bs   = (float*)(ws + 16551936);     // 4,096 B
  float* sums = (float*)(ws + 16556032);     // 32 B
  float* maxg = (float*)(ws + 16556096);     // 32 B

  k0a_wt   <<<dim3(10, 24),  dim3(256), 0, stream>>>(Ww, Wt);
  k0b_bt   <<<dim3(320),     dim3(128), 0, stream>>>(a1w, Bt2);
  k1_h     <<<dim3(640),     dim3(128), 0, stream>>>(feat, Wt, Wb, H);
  k2_s     <<<dim3(2, 128),  dim3(128), 0, stream>>>(H, Bt2, a1b, S);
  k3_logits<<<dim3(8, 16, 8),dim3(256), 0, stream>>>(S, adj, a2w, a2b, L, bm, bs);
  k6_red   <<<dim3(8),       dim3(128), 0, stream>>>(bm, bs, sums, maxg);
  k7_out   <<<dim3(640),     dim3(128), 0, stream>>>(L, H, sums, maxg, out);
}

// Round 10
// 172.346 us; speedup vs baseline: 1.1674x; 1.1674x over previous
//
#include <hip/hip_runtime.h>
// R10: 2-wave 64x64 GEMM blocks (k1,k7), kc=32 dbuf, 1 barrier/tile, swizzled LDS;
// fits proven 15.4MB ws (no split-K buffers). k2 coalesced A-staging. k3: uniform
// s_load si/w + stride-68 sj tile (LDS floor, no XOR). k7 writes out directly.

#define NEGINF (-1e30f)

__device__ inline float waveRedSum(float v){
  #pragma unroll
  for (int o = 32; o > 0; o >>= 1) v += __shfl_down(v, o, 64);
  return v;
}
__device__ inline float waveRedMax(float v){
  #pragma unroll
  for (int o = 32; o > 0; o >>= 1) v = fmaxf(v, __shfl_down(v, o, 64));
  return v;
}
__device__ inline float4 f4z(){ return make_float4(0.f,0.f,0.f,0.f); }
#define F4C(v, c) ((c)==0?(v).x:(c)==1?(v).y:(c)==2?(v).z:(v).w)

// ================= K1: H = feat @ W^T + Wb  [4096 x 300], K=768 ====================
// 128 thr (2 waves), tile 64Mx64N, 8x4 acc/thread. grid 320 (8 XCD-chunks x 40).
__global__ __launch_bounds__(128) void k1_h(const float* __restrict__ A,
                                            const float* __restrict__ W,
                                            const float* __restrict__ Wb,
                                            float* __restrict__ H){
  __shared__ float As[2][32*72];
  __shared__ float Bs[2][32*72];
  const int fid = blockIdx.x;
  const int wl  = (fid & 7) * 40 + (fid >> 3);
  const int y = wl / 5, x = wl % 5;
  const int m0 = y * 64, c0 = x * 64;
  const int t = threadIdx.x;
  const int lane = t & 63, wv = t >> 6;
  const int g8 = wv * 4 + (lane >> 4);       // 8-row group 0..7
  const int c4 = lane & 15;                  // 4-col chunk 0..15
  const int srow = lane, skb = wv * 16;
  const bool bok = (c0 + srow) < 300;
  const float* Ap = A + (size_t)(m0 + srow) * 768 + skb;
  const float* Wp = W + (size_t)(c0 + srow) * 768 + skb;
  float4 a4[4], b4[4];
  float4 acc[8];
  #pragma unroll
  for (int i = 0; i < 8; i++) acc[i] = f4z();
  #pragma unroll
  for (int j = 0; j < 4; j++){
    a4[j] = *(const float4*)(Ap + 4*j);
    b4[j] = bok ? *(const float4*)(Wp + 4*j) : f4z();
  }
  int p = 0;
  for (int tile = 0; tile < 24; ++tile){
    #pragma unroll
    for (int jj = 0; jj < 16; jj++){
      const int k = skb + jj;
      const int sw = (k >> 2) & 3;
      const int pos = (((srow >> 2) ^ sw) << 2) | (srow & 3);
      As[p][k*72 + pos] = F4C(a4[jj>>2], jj&3);
      Bs[p][k*72 + pos] = F4C(b4[jj>>2], jj&3);
    }
    __syncthreads();
    if (tile < 23){
      const int ofs = (tile + 1) * 32;
      #pragma unroll
      for (int j = 0; j < 4; j++){
        a4[j] = *(const float4*)(Ap + ofs + 4*j);
        b4[j] = bok ? *(const float4*)(Wp + ofs + 4*j) : f4z();
      }
    }
    #pragma unroll
    for (int kk = 0; kk < 32; kk++){
      const int sw = (kk >> 2) & 3;
      const float4 aL = *(const float4*)&As[p][kk*72 + (((2*g8    ) ^ sw) << 2)];
      const float4 aH = *(const float4*)&As[p][kk*72 + (((2*g8 + 1) ^ sw) << 2)];
      const float4 bv = *(const float4*)&Bs[p][kk*72 + ((c4 ^ sw) << 2)];
      const float am[8] = {aL.x,aL.y,aL.z,aL.w,aH.x,aH.y,aH.z,aH.w};
      #pragma unroll
      for (int i = 0; i < 8; i++){
        acc[i].x += am[i]*bv.x; acc[i].y += am[i]*bv.y;
        acc[i].z += am[i]*bv.z; acc[i].w += am[i]*bv.w;
      }
    }
    p ^= 1;
  }
  const int col = c0 + c4*4;
  if (col < 300){
    const float4 bi = *(const float4*)&Wb[col];
    #pragma unroll
    for (int i = 0; i < 8; i++){
      float4 o = make_float4(acc[i].x+bi.x, acc[i].y+bi.y, acc[i].z+bi.z, acc[i].w+bi.w);
      *(float4*)&H[(size_t)(m0 + g8*8 + i) * 300 + col] = o;
    }
  }
}

// ================= K2: S = H @ Bmat^T (+a1b cols<64)  [4096 x 128], K=300 ==========
// 256 thr, tile 32M x 128N, 4x4 acc, kc=32 dbuf, 1 barrier. grid 128.
__global__ __launch_bounds__(256) void k2_s(const float* __restrict__ Hm,
                                            const float* __restrict__ a1w,
                                            const float* __restrict__ a1b,
                                            float* __restrict__ S){
  __shared__ float As[2][32*40];
  __shared__ float Bs[2][32*136];
  const int bid = blockIdx.x;
  const int y = (bid & 7) * 16 + (bid >> 3);
  const int m0 = y * 32;
  const int t = threadIdx.x;
  const int tr4 = (t >> 5) * 4, tc = t & 31;
  const int arow = t >> 3, akq = t & 7;       // A: row 0..31, k-quad 0..7
  const int bn = t & 127, bkh = t >> 7;       // B: col 0..127, k-half 0..1
  const float* brp = (bn < 64) ? &a1w[(size_t)bn * 600] : &a1w[(size_t)(bn - 64) * 600 + 300];
  float4 ha, b4[4];
  float4 acc[4];
  #pragma unroll
  for (int i = 0; i < 4; i++) acc[i] = f4z();
#define K2_LD(kt) { \
    const int ka = (kt) + akq*4; \
    ha = (ka < 300) ? *(const float4*)&Hm[(size_t)(m0 + arow)*300 + ka] : f4z(); \
    _Pragma("unroll") \
    for (int j = 0; j < 4; j++){ \
      const int kb = (kt) + bkh*16 + 4*j; \
      b4[j] = (kb < 300) ? *(const float4*)&brp[kb] : f4z(); \
    } }
  K2_LD(0)
  int p = 0;
  for (int tile = 0; tile < 10; ++tile){
    #pragma unroll
    for (int jj = 0; jj < 4; jj++)
      As[p][(akq*4 + jj)*40 + ((((arow>>2) ^ akq) & 7) << 2) + (arow & 3)] = F4C(ha, jj);
    #pragma unroll
    for (int jj = 0; jj < 16; jj++){
      const int kl = bkh*16 + jj;
      const int swb = (kl >> 2) & 7;
      Bs[p][kl*136 + (((bn>>2) ^ swb) << 2) + (bn & 3)] = F4C(b4[jj>>2], jj&3);
    }
    __syncthreads();
    if (tile < 9) K2_LD((tile + 1) * 32)
    #pragma unroll
    for (int kk = 0; kk < 32; kk++){
      const int sw = (kk >> 2) & 7;
      const float4 av = *(const float4*)&As[p][kk*40 + (((t>>5) ^ sw) << 2)];
      const float4 bv = *(const float4*)&Bs[p][kk*136 + ((tc ^ sw) << 2)];
      acc[0].x += av.x*bv.x; acc[0].y += av.x*bv.y; acc[0].z += av.x*bv.z; acc[0].w += av.x*bv.w;
      acc[1].x += av.y*bv.x; acc[1].y += av.y*bv.y; acc[1].z += av.y*bv.z; acc[1].w += av.y*bv.w;
      acc[2].x += av.z*bv.x; acc[2].y += av.z*bv.y; acc[2].z += av.z*bv.z; acc[2].w += av.z*bv.w;
      acc[3].x += av.w*bv.x; acc[3].y += av.w*bv.y; acc[3].z += av.w*bv.z; acc[3].w += av.w*bv.w;
    }
    p ^= 1;
  }
#undef K2_LD
  const int tc4 = tc * 4;
  float4 bi = f4z();
  if (tc4 < 64) bi = *(const float4*)&a1b[tc4];
  #pragma unroll
  for (int i = 0; i < 4; i++){
    float4 o = make_float4(acc[i].x+bi.x, acc[i].y+bi.y, acc[i].z+bi.z, acc[i].w+bi.w);
    *(float4*)&S[(size_t)(m0 + tr4 + i) * 128 + tc4] = o;
  }
}

// ================= K3: logits + mask + per-block (max, sum-exp) =====================
// sj tile stride 68 (17x16B, quad-coprime): b128 reads at LDS floor, no swizzle.
__global__ __launch_bounds__(256) void k3_logits(const float* __restrict__ S,
                                                 const float* __restrict__ adj,
                                                 const float* __restrict__ a2w,
                                                 const float* __restrict__ a2b,
                                                 float* __restrict__ L,
                                                 float* __restrict__ bm,
                                                 float* __restrict__ bs){
  __shared__ float sj_s[64*68];
  __shared__ float redm[4];
  __shared__ float reds[4];
  __shared__ float smax;
  const int b  = blockIdx.z;
  const int i0 = blockIdx.y * 32;
  const int j0 = blockIdx.x * 64;
  const int t  = threadIdx.x;
  #pragma unroll
  for (int q = 0; q < 4; q++){
    int c = t + q*256; int r = c >> 4, c4 = c & 15;
    float4 v = *(const float4*)&S[(size_t)(b*512 + j0 + r)*128 + 64 + c4*4];
    *(float4*)&sj_s[r*68 + c4*4] = v;
  }
  __syncthreads();
  const int j = t & 63;
  const int iqu = __builtin_amdgcn_readfirstlane(t >> 6);   // wave-uniform
  const float* __restrict__ Sband = S + (size_t)(b*512 + i0 + iqu) * 128;
  const float a2bv = a2b[0];
  float4 acc[8];
  #pragma unroll
  for (int ii = 0; ii < 8; ii++) acc[ii] = f4z();
  #pragma unroll
  for (int k4 = 0; k4 < 16; k4++){
    const float4 sj4 = *(const float4*)&sj_s[j*68 + k4*4];
    const float4 w4  = *(const float4*)&a2w[k4*4];           // uniform -> s_load
    #pragma unroll
    for (int ii = 0; ii < 8; ii++){
      const float4 si4 = *(const float4*)&Sband[(size_t)(ii*4)*128 + k4*4]; // uniform
      acc[ii].x += fmaxf(si4.x + sj4.x, 0.f) * w4.x;
      acc[ii].y += fmaxf(si4.y + sj4.y, 0.f) * w4.y;
      acc[ii].z += fmaxf(si4.z + sj4.z, 0.f) * w4.z;
      acc[ii].w += fmaxf(si4.w + sj4.w, 0.f) * w4.w;
    }
  }
  float l_arr[8];
  float locmax = -3e38f;
  #pragma unroll
  for (int ii = 0; ii < 8; ii++){
    const int i = ii*4 + iqu;
    float e = ((acc[ii].x + acc[ii].y) + (acc[ii].z + acc[ii].w)) + a2bv;
    e = (e >= 0.f) ? e : 0.01f * e;
    size_t idxg = (size_t)(b*512 + i0 + i)*512 + j0 + j;
    float l = (adj[idxg] != 0.f) ? e : NEGINF;
    l_arr[ii] = l;
    L[idxg] = l;
    locmax = fmaxf(locmax, l);
  }
  float m = waveRedMax(locmax);
  if ((t & 63) == 0) redm[t >> 6] = m;
  __syncthreads();
  if (t == 0) smax = fmaxf(fmaxf(redm[0], redm[1]), fmaxf(redm[2], redm[3]));
  __syncthreads();
  const float mb = smax;
  float sacc = 0.f;
  #pragma unroll
  for (int ii = 0; ii < 8; ii++) sacc += __expf(l_arr[ii] - mb);
  sacc = waveRedSum(sacc);
  if ((t & 63) == 0) reds[t >> 6] = sacc;
  __syncthreads();
  if (t == 0){
    const int bid = (blockIdx.z * 16 + blockIdx.y) * 8 + blockIdx.x;
    bm[bid] = mb;
    bs[bid] = (reds[0] + reds[1]) + (reds[2] + reds[3]);
  }
}

// ================= K6: combine per-block (m,s) -> per-batch (maxg, sums) ============
__global__ __launch_bounds__(128) void k6_red(const float* __restrict__ bm,
                                              const float* __restrict__ bs,
                                              float* __restrict__ sums,
                                              float* __restrict__ maxg){
  const int b = blockIdx.x, t = threadIdx.x;
  const float m = bm[b*128 + t];
  float mm = waveRedMax(m);
  __shared__ float r2m[2];
  __shared__ float mgs;
  if ((t & 63) == 0) r2m[t >> 6] = mm;
  __syncthreads();
  if (t == 0) mgs = fmaxf(r2m[0], r2m[1]);
  __syncthreads();
  const float mg = mgs;
  float v = bs[b*128 + t] * __expf(m - mg);
  v = waveRedSum(v);
  __shared__ float r2s[2];
  if ((t & 63) == 0) r2s[t >> 6] = v;
  __syncthreads();
  if (t == 0){ sums[b] = r2s[0] + r2s[1]; maxg[b] = mg; }
}

// ================= K7: out = (exp(L-maxg) @ H) / sums; per-batch [512x300] ==========
// 128 thr, 64x64 tile, 8x4 acc, kc=32 dbuf, 1 barrier. grid 320 (batch = fid&7).
__global__ __launch_bounds__(128) void k7_out(const float* __restrict__ Lr,
                                              const float* __restrict__ Hm,
                                              const float* __restrict__ sums,
                                              const float* __restrict__ maxg,
                                              float* __restrict__ out){
  __shared__ float As[2][32*72];
  __shared__ float Bs[2][32*72];
  const int fid = blockIdx.x;
  const int b  = fid & 7;
  const int idx = fid >> 3;
  const int y = idx / 5, x = idx % 5;
  const int m0 = y * 64, c0 = x * 64;
  const int t = threadIdx.x;
  const int lane = t & 63, wv = t >> 6;
  const int g8 = wv * 4 + (lane >> 4);
  const int c4 = lane & 15;
  const int srow = lane, skb = wv * 16;
  const int kr = t >> 2, cq = t & 3;          // B staging: k-row 0..31, col-quarter
  const float mx = maxg[b];
  const float* Lp = Lr + (size_t)(b*512 + m0 + srow) * 512 + skb;
  const float* Hb = Hm + (size_t)(b*512) * 300;
  float4 a4[4], b4[4];
  float4 acc[8];
  #pragma unroll
  for (int i = 0; i < 8; i++) acc[i] = f4z();
#define K7_LDB(kt) { \
    const float* hr = Hb + (size_t)((kt) + kr) * 300; \
    _Pragma("unroll") \
    for (int j = 0; j < 4; j++){ \
      const int colj = c0 + cq*16 + 4*j; \
      b4[j] = (colj < 300) ? *(const float4*)&hr[colj] : f4z(); \
    } }
  #pragma unroll
  for (int j = 0; j < 4; j++) a4[j] = *(const float4*)(Lp + 4*j);
  K7_LDB(0)
  int p = 0;
  for (int tile = 0; tile < 16; ++tile){
    #pragma unroll
    for (int jj = 0; jj < 16; jj++){
      const int k = skb + jj;
      const int sw = (k >> 2) & 3;
      const int pos = (((srow >> 2) ^ sw) << 2) | (srow & 3);
      As[p][k*72 + pos] = __expf(F4C(a4[jj>>2], jj&3) - mx);
    }
    {
      const int swb = (kr >> 2) & 3;
      #pragma unroll
      for (int j = 0; j < 4; j++)
        *(float4*)&Bs[p][kr*72 + (((cq*4 + j) ^ swb) << 2)] = b4[j];
    }
    __syncthreads();
    if (tile < 15){
      const int ofs = (tile + 1) * 32;
      #pragma unroll
      for (int j = 0; j < 4; j++) a4[j] = *(const float4*)(Lp + ofs + 4*j);
      K7_LDB(ofs)
    }
    #pragma unroll
    for (int kk = 0; kk < 32; kk++){
      const int sw = (kk >> 2) & 3;
      const float4 aL = *(const float4*)&As[p][kk*72 + (((2*g8    ) ^ sw) << 2)];
      const float4 aH = *(const float4*)&As[p][kk*72 + (((2*g8 + 1) ^ sw) << 2)];
      const float4 bv = *(const float4*)&Bs[p][kk*72 + ((c4 ^ sw) << 2)];
      const float am[8] = {aL.x,aL.y,aL.z,aL.w,aH.x,aH.y,aH.z,aH.w};
      #pragma unroll
      for (int i = 0; i < 8; i++){
        acc[i].x += am[i]*bv.x; acc[i].y += am[i]*bv.y;
        acc[i].z += am[i]*bv.z; acc[i].w += am[i]*bv.w;
      }
    }
    p ^= 1;
  }
#undef K7_LDB
  const int col = c0 + c4*4;
  if (col < 300){
    const float invs = 1.0f / sums[b];
    #pragma unroll
    for (int i = 0; i < 8; i++){
      float4 o = make_float4(acc[i].x*invs, acc[i].y*invs, acc[i].z*invs, acc[i].w*invs);
      *(float4*)&out[(size_t)(b*512 + m0 + g8*8 + i) * 300 + col] = o;
    }
  }
}

extern "C" void kernel_launch(void* const* d_in, const int* in_sizes, int n_in,
                              void* d_out, int out_size, void* d_ws, size_t ws_size,
                              hipStream_t stream){
  const float* adj  = (const float*)d_in[0];
  const float* feat = (const float*)d_in[1];
  const float* Ww   = (const float*)d_in[2];
  const float* Wb   = (const float*)d_in[3];
  const float* a1w  = (const float*)d_in[4];
  const float* a1b  = (const float*)d_in[5];
  const float* a2w  = (const float*)d_in[6];
  const float* a2b  = (const float*)d_in[7];
  float* out = (float*)d_out;
  char* ws = (char*)d_ws;

  float* H    = (float*)(ws + 0);           // 4,915,200 B
  float* S    = (float*)(ws + 4915200);     // 2,097,152 B
  float* L    = (float*)(ws + 7012352);     // 8,388,608 B
  float* bm   = (float*)(ws + 15400960);    // 4,096 B
  float* bs   = (float*)(ws + 15405056);    // 4,096 B
  float* sums = (float*)(ws + 15409152);    // 32 B
  float* maxg = (float*)(ws + 15409216);    // 32 B

  k1_h     <<<dim3(320),      dim3(128), 0, stream>>>(feat, Ww, Wb, H);
  k2_s     <<<dim3(128),      dim3(256), 0, stream>>>(H, a1w, a1b, S);
  k3_logits<<<dim3(8, 16, 8), dim3(256), 0, stream>>>(S, adj, a2w, a2b, L, bm, bs);
  k6_red   <<<dim3(8),        dim3(128), 0, stream>>>(bm, bs, sums, maxg);
  k7_out   <<<dim3(320),      dim3(128), 0, stream>>>(L, H, sums, maxg, out);
}

// Round 11
// 156.902 us; speedup vs baseline: 1.2823x; 1.0984x over previous
//
#include <hip/hip_runtime.h>
// R11: revert k3 to LDS-staged si/w (R10's s_load-si regressed k3 25->65us);
// keep stride-68 conflict-free sj tile (measured 0 conflicts). k1/k2/k7/k6
// byte-identical to R10.

#define NEGINF (-1e30f)

__device__ inline float waveRedSum(float v){
  #pragma unroll
  for (int o = 32; o > 0; o >>= 1) v += __shfl_down(v, o, 64);
  return v;
}
__device__ inline float waveRedMax(float v){
  #pragma unroll
  for (int o = 32; o > 0; o >>= 1) v = fmaxf(v, __shfl_down(v, o, 64));
  return v;
}
__device__ inline float4 f4z(){ return make_float4(0.f,0.f,0.f,0.f); }
#define F4C(v, c) ((c)==0?(v).x:(c)==1?(v).y:(c)==2?(v).z:(v).w)

// ================= K1: H = feat @ W^T + Wb  [4096 x 300], K=768 ====================
// 128 thr (2 waves), tile 64Mx64N, 8x4 acc/thread. grid 320 (8 XCD-chunks x 40).
__global__ __launch_bounds__(128) void k1_h(const float* __restrict__ A,
                                            const float* __restrict__ W,
                                            const float* __restrict__ Wb,
                                            float* __restrict__ H){
  __shared__ float As[2][32*72];
  __shared__ float Bs[2][32*72];
  const int fid = blockIdx.x;
  const int wl  = (fid & 7) * 40 + (fid >> 3);
  const int y = wl / 5, x = wl % 5;
  const int m0 = y * 64, c0 = x * 64;
  const int t = threadIdx.x;
  const int lane = t & 63, wv = t >> 6;
  const int g8 = wv * 4 + (lane >> 4);       // 8-row group 0..7
  const int c4 = lane & 15;                  // 4-col chunk 0..15
  const int srow = lane, skb = wv * 16;
  const bool bok = (c0 + srow) < 300;
  const float* Ap = A + (size_t)(m0 + srow) * 768 + skb;
  const float* Wp = W + (size_t)(c0 + srow) * 768 + skb;
  float4 a4[4], b4[4];
  float4 acc[8];
  #pragma unroll
  for (int i = 0; i < 8; i++) acc[i] = f4z();
  #pragma unroll
  for (int j = 0; j < 4; j++){
    a4[j] = *(const float4*)(Ap + 4*j);
    b4[j] = bok ? *(const float4*)(Wp + 4*j) : f4z();
  }
  int p = 0;
  for (int tile = 0; tile < 24; ++tile){
    #pragma unroll
    for (int jj = 0; jj < 16; jj++){
      const int k = skb + jj;
      const int sw = (k >> 2) & 3;
      const int pos = (((srow >> 2) ^ sw) << 2) | (srow & 3);
      As[p][k*72 + pos] = F4C(a4[jj>>2], jj&3);
      Bs[p][k*72 + pos] = F4C(b4[jj>>2], jj&3);
    }
    __syncthreads();
    if (tile < 23){
      const int ofs = (tile + 1) * 32;
      #pragma unroll
      for (int j = 0; j < 4; j++){
        a4[j] = *(const float4*)(Ap + ofs + 4*j);
        b4[j] = bok ? *(const float4*)(Wp + ofs + 4*j) : f4z();
      }
    }
    #pragma unroll
    for (int kk = 0; kk < 32; kk++){
      const int sw = (kk >> 2) & 3;
      const float4 aL = *(const float4*)&As[p][kk*72 + (((2*g8    ) ^ sw) << 2)];
      const float4 aH = *(const float4*)&As[p][kk*72 + (((2*g8 + 1) ^ sw) << 2)];
      const float4 bv = *(const float4*)&Bs[p][kk*72 + ((c4 ^ sw) << 2)];
      const float am[8] = {aL.x,aL.y,aL.z,aL.w,aH.x,aH.y,aH.z,aH.w};
      #pragma unroll
      for (int i = 0; i < 8; i++){
        acc[i].x += am[i]*bv.x; acc[i].y += am[i]*bv.y;
        acc[i].z += am[i]*bv.z; acc[i].w += am[i]*bv.w;
      }
    }
    p ^= 1;
  }
  const int col = c0 + c4*4;
  if (col < 300){
    const float4 bi = *(const float4*)&Wb[col];
    #pragma unroll
    for (int i = 0; i < 8; i++){
      float4 o = make_float4(acc[i].x+bi.x, acc[i].y+bi.y, acc[i].z+bi.z, acc[i].w+bi.w);
      *(float4*)&H[(size_t)(m0 + g8*8 + i) * 300 + col] = o;
    }
  }
}

// ================= K2: S = H @ Bmat^T (+a1b cols<64)  [4096 x 128], K=300 ==========
__global__ __launch_bounds__(256) void k2_s(const float* __restrict__ Hm,
                                            const float* __restrict__ a1w,
                                            const float* __restrict__ a1b,
                                            float* __restrict__ S){
  __shared__ float As[2][32*40];
  __shared__ float Bs[2][32*136];
  const int bid = blockIdx.x;
  const int y = (bid & 7) * 16 + (bid >> 3);
  const int m0 = y * 32;
  const int t = threadIdx.x;
  const int tr4 = (t >> 5) * 4, tc = t & 31;
  const int arow = t >> 3, akq = t & 7;
  const int bn = t & 127, bkh = t >> 7;
  const float* brp = (bn < 64) ? &a1w[(size_t)bn * 600] : &a1w[(size_t)(bn - 64) * 600 + 300];
  float4 ha, b4[4];
  float4 acc[4];
  #pragma unroll
  for (int i = 0; i < 4; i++) acc[i] = f4z();
#define K2_LD(kt) { \
    const int ka = (kt) + akq*4; \
    ha = (ka < 300) ? *(const float4*)&Hm[(size_t)(m0 + arow)*300 + ka] : f4z(); \
    _Pragma("unroll") \
    for (int j = 0; j < 4; j++){ \
      const int kb = (kt) + bkh*16 + 4*j; \
      b4[j] = (kb < 300) ? *(const float4*)&brp[kb] : f4z(); \
    } }
  K2_LD(0)
  int p = 0;
  for (int tile = 0; tile < 10; ++tile){
    #pragma unroll
    for (int jj = 0; jj < 4; jj++)
      As[p][(akq*4 + jj)*40 + ((((arow>>2) ^ akq) & 7) << 2) + (arow & 3)] = F4C(ha, jj);
    #pragma unroll
    for (int jj = 0; jj < 16; jj++){
      const int kl = bkh*16 + jj;
      const int swb = (kl >> 2) & 7;
      Bs[p][kl*136 + (((bn>>2) ^ swb) << 2) + (bn & 3)] = F4C(b4[jj>>2], jj&3);
    }
    __syncthreads();
    if (tile < 9) K2_LD((tile + 1) * 32)
    #pragma unroll
    for (int kk = 0; kk < 32; kk++){
      const int sw = (kk >> 2) & 7;
      const float4 av = *(const float4*)&As[p][kk*40 + (((t>>5) ^ sw) << 2)];
      const float4 bv = *(const float4*)&Bs[p][kk*136 + ((tc ^ sw) << 2)];
      acc[0].x += av.x*bv.x; acc[0].y += av.x*bv.y; acc[0].z += av.x*bv.z; acc[0].w += av.x*bv.w;
      acc[1].x += av.y*bv.x; acc[1].y += av.y*bv.y; acc[1].z += av.y*bv.z; acc[1].w += av.y*bv.w;
      acc[2].x += av.z*bv.x; acc[2].y += av.z*bv.y; acc[2].z += av.z*bv.z; acc[2].w += av.z*bv.w;
      acc[3].x += av.w*bv.x; acc[3].y += av.w*bv.y; acc[3].z += av.w*bv.z; acc[3].w += av.w*bv.w;
    }
    p ^= 1;
  }
#undef K2_LD
  const int tc4 = tc * 4;
  float4 bi = f4z();
  if (tc4 < 64) bi = *(const float4*)&a1b[tc4];
  #pragma unroll
  for (int i = 0; i < 4; i++){
    float4 o = make_float4(acc[i].x+bi.x, acc[i].y+bi.y, acc[i].z+bi.z, acc[i].w+bi.w);
    *(float4*)&S[(size_t)(m0 + tr4 + i) * 128 + tc4] = o;
  }
}

// ================= K3: logits + mask + per-block (max, sum-exp) =====================
// si/w staged in LDS (broadcast reads); sj stride-68 (measured 0 conflicts).
__global__ __launch_bounds__(256) void k3_logits(const float* __restrict__ S,
                                                 const float* __restrict__ adj,
                                                 const float* __restrict__ a2w,
                                                 const float* __restrict__ a2b,
                                                 float* __restrict__ L,
                                                 float* __restrict__ bm,
                                                 float* __restrict__ bs){
  __shared__ float si_s[32*68];
  __shared__ float sj_s[64*68];
  __shared__ float w_s[64];
  __shared__ float redm[4];
  __shared__ float reds[4];
  __shared__ float smax;
  const int b  = blockIdx.z;
  const int i0 = blockIdx.y * 32;
  const int j0 = blockIdx.x * 64;
  const int t  = threadIdx.x;
  if (t < 16) *(float4*)&w_s[t*4] = *(const float4*)&a2w[t*4];
  #pragma unroll
  for (int q = 0; q < 2; q++){
    int c = t + q*256; int r = c >> 4, c4 = c & 15;
    *(float4*)&si_s[r*68 + c4*4] = *(const float4*)&S[(size_t)(b*512 + i0 + r)*128 + c4*4];
  }
  #pragma unroll
  for (int q = 0; q < 4; q++){
    int c = t + q*256; int r = c >> 4, c4 = c & 15;
    *(float4*)&sj_s[r*68 + c4*4] = *(const float4*)&S[(size_t)(b*512 + j0 + r)*128 + 64 + c4*4];
  }
  __syncthreads();
  const int j = t & 63, iq = t >> 6;
  const float a2bv = a2b[0];
  float4 acc[8];
  #pragma unroll
  for (int ii = 0; ii < 8; ii++) acc[ii] = f4z();
  #pragma unroll
  for (int k4 = 0; k4 < 16; k4++){
    const float4 sj4 = *(const float4*)&sj_s[j*68 + k4*4];
    const float4 w4  = *(const float4*)&w_s[k4*4];
    #pragma unroll
    for (int ii = 0; ii < 8; ii++){
      const int i = ii*4 + iq;                 // wave-uniform -> LDS broadcast
      const float4 si4 = *(const float4*)&si_s[i*68 + k4*4];
      acc[ii].x += fmaxf(si4.x + sj4.x, 0.f) * w4.x;
      acc[ii].y += fmaxf(si4.y + sj4.y, 0.f) * w4.y;
      acc[ii].z += fmaxf(si4.z + sj4.z, 0.f) * w4.z;
      acc[ii].w += fmaxf(si4.w + sj4.w, 0.f) * w4.w;
    }
  }
  float l_arr[8];
  float locmax = -3e38f;
  #pragma unroll
  for (int ii = 0; ii < 8; ii++){
    const int i = ii*4 + iq;
    float e = ((acc[ii].x + acc[ii].y) + (acc[ii].z + acc[ii].w)) + a2bv;
    e = (e >= 0.f) ? e : 0.01f * e;
    size_t idxg = (size_t)(b*512 + i0 + i)*512 + j0 + j;
    float l = (adj[idxg] != 0.f) ? e : NEGINF;
    l_arr[ii] = l;
    L[idxg] = l;
    locmax = fmaxf(locmax, l);
  }
  float m = waveRedMax(locmax);
  if ((t & 63) == 0) redm[t >> 6] = m;
  __syncthreads();
  if (t == 0) smax = fmaxf(fmaxf(redm[0], redm[1]), fmaxf(redm[2], redm[3]));
  __syncthreads();
  const float mb = smax;
  float sacc = 0.f;
  #pragma unroll
  for (int ii = 0; ii < 8; ii++) sacc += __expf(l_arr[ii] - mb);
  sacc = waveRedSum(sacc);
  if ((t & 63) == 0) reds[t >> 6] = sacc;
  __syncthreads();
  if (t == 0){
    const int bid = (blockIdx.z * 16 + blockIdx.y) * 8 + blockIdx.x;
    bm[bid] = mb;
    bs[bid] = (reds[0] + reds[1]) + (reds[2] + reds[3]);
  }
}

// ================= K6: combine per-block (m,s) -> per-batch (maxg, sums) ============
__global__ __launch_bounds__(128) void k6_red(const float* __restrict__ bm,
                                              const float* __restrict__ bs,
                                              float* __restrict__ sums,
                                              float* __restrict__ maxg){
  const int b = blockIdx.x, t = threadIdx.x;
  const float m = bm[b*128 + t];
  float mm = waveRedMax(m);
  __shared__ float r2m[2];
  __shared__ float mgs;
  if ((t & 63) == 0) r2m[t >> 6] = mm;
  __syncthreads();
  if (t == 0) mgs = fmaxf(r2m[0], r2m[1]);
  __syncthreads();
  const float mg = mgs;
  float v = bs[b*128 + t] * __expf(m - mg);
  v = waveRedSum(v);
  __shared__ float r2s[2];
  if ((t & 63) == 0) r2s[t >> 6] = v;
  __syncthreads();
  if (t == 0){ sums[b] = r2s[0] + r2s[1]; maxg[b] = mg; }
}

// ================= K7: out = (exp(L-maxg) @ H) / sums; per-batch [512x300] ==========
__global__ __launch_bounds__(128) void k7_out(const float* __restrict__ Lr,
                                              const float* __restrict__ Hm,
                                              const float* __restrict__ sums,
                                              const float* __restrict__ maxg,
                                              float* __restrict__ out){
  __shared__ float As[2][32*72];
  __shared__ float Bs[2][32*72];
  const int fid = blockIdx.x;
  const int b  = fid & 7;
  const int idx = fid >> 3;
  const int y = idx / 5, x = idx % 5;
  const int m0 = y * 64, c0 = x * 64;
  const int t = threadIdx.x;
  const int lane = t & 63, wv = t >> 6;
  const int g8 = wv * 4 + (lane >> 4);
  const int c4 = lane & 15;
  const int srow = lane, skb = wv * 16;
  const int kr = t >> 2, cq = t & 3;
  const float mx = maxg[b];
  const float* Lp = Lr + (size_t)(b*512 + m0 + srow) * 512 + skb;
  const float* Hb = Hm + (size_t)(b*512) * 300;
  float4 a4[4], b4[4];
  float4 acc[8];
  #pragma unroll
  for (int i = 0; i < 8; i++) acc[i] = f4z();
#define K7_LDB(kt) { \
    const float* hr = Hb + (size_t)((kt) + kr) * 300; \
    _Pragma("unroll") \
    for (int j = 0; j < 4; j++){ \
      const int colj = c0 + cq*16 + 4*j; \
      b4[j] = (colj < 300) ? *(const float4*)&hr[colj] : f4z(); \
    } }
  #pragma unroll
  for (int j = 0; j < 4; j++) a4[j] = *(const float4*)(Lp + 4*j);
  K7_LDB(0)
  int p = 0;
  for (int tile = 0; tile < 16; ++tile){
    #pragma unroll
    for (int jj = 0; jj < 16; jj++){
      const int k = skb + jj;
      const int sw = (k >> 2) & 3;
      const int pos = (((srow >> 2) ^ sw) << 2) | (srow & 3);
      As[p][k*72 + pos] = __expf(F4C(a4[jj>>2], jj&3) - mx);
    }
    {
      const int swb = (kr >> 2) & 3;
      #pragma unroll
      for (int j = 0; j < 4; j++)
        *(float4*)&Bs[p][kr*72 + (((cq*4 + j) ^ swb) << 2)] = b4[j];
    }
    __syncthreads();
    if (tile < 15){
      const int ofs = (tile + 1) * 32;
      #pragma unroll
      for (int j = 0; j < 4; j++) a4[j] = *(const float4*)(Lp + ofs + 4*j);
      K7_LDB(ofs)
    }
    #pragma unroll
    for (int kk = 0; kk < 32; kk++){
      const int sw = (kk >> 2) & 3;
      const float4 aL = *(const float4*)&As[p][kk*72 + (((2*g8    ) ^ sw) << 2)];
      const float4 aH = *(const float4*)&As[p][kk*72 + (((2*g8 + 1) ^ sw) << 2)];
      const float4 bv = *(const float4*)&Bs[p][kk*72 + ((c4 ^ sw) << 2)];
      const float am[8] = {aL.x,aL.y,aL.z,aL.w,aH.x,aH.y,aH.z,aH.w};
      #pragma unroll
      for (int i = 0; i < 8; i++){
        acc[i].x += am[i]*bv.x; acc[i].y += am[i]*bv.y;
        acc[i].z += am[i]*bv.z; acc[i].w += am[i]*bv.w;
      }
    }
    p ^= 1;
  }
#undef K7_LDB
  const int col = c0 + c4*4;
  if (col < 300){
    const float invs = 1.0f / sums[b];
    #pragma unroll
    for (int i = 0; i < 8; i++){
      float4 o = make_float4(acc[i].x*invs, acc[i].y*invs, acc[i].z*invs, acc[i].w*invs);
      *(float4*)&out[(size_t)(b*512 + m0 + g8*8 + i) * 300 + col] = o;
    }
  }
}

extern "C" void kernel_launch(void* const* d_in, const int* in_sizes, int n_in,
                              void* d_out, int out_size, void* d_ws, size_t ws_size,
                              hipStream_t stream){
  const float* adj  = (const float*)d_in[0];
  const float* feat = (const float*)d_in[1];
  const float* Ww   = (const float*)d_in[2];
  const float* Wb   = (const float*)d_in[3];
  const float* a1w  = (const float*)d_in[4];
  const float* a1b  = (const float*)d_in[5];
  const float* a2w  = (const float*)d_in[6];
  const float* a2b  = (const float*)d_in[7];
  float* out = (float*)d_out;
  char* ws = (char*)d_ws;

  float* H    = (float*)(ws + 0);           // 4,915,200 B
  float* S    = (float*)(ws + 4915200);     // 2,097,152 B
  float* L    = (float*)(ws + 7012352);     // 8,388,608 B
  float* bm   = (float*)(ws + 15400960);    // 4,096 B
  float* bs   = (float*)(ws + 15405056);    // 4,096 B
  float* sums = (float*)(ws + 15409152);    // 32 B
  float* maxg = (float*)(ws + 15409216);    // 32 B

  k1_h     <<<dim3(320),      dim3(128), 0, stream>>>(feat, Ww, Wb, H);
  k2_s     <<<dim3(128),      dim3(256), 0, stream>>>(H, a1w, a1b, S);
  k3_logits<<<dim3(8, 16, 8), dim3(256), 0, stream>>>(S, adj, a2w, a2b, L, bm, bs);
  k6_red   <<<dim3(8),        dim3(128), 0, stream>>>(bm, bs, sums, maxg);
  k7_out   <<<dim3(320),      dim3(128), 0, stream>>>(L, H, sums, maxg, out);
}

// Round 12
// 153.132 us; speedup vs baseline: 1.3138x; 1.0246x over previous
//
#include <hip/hip_runtime.h>
// R12: k1/k7 -> 4-wave in-block split-K, 64x64 tile, 8x8 acc/thread, per-wave
// single-buffer swizzled LDS (zero per-tile barriers), end-of-block LDS combine.
// Per-wave serial FMA time drops 4x (20us -> 5-10us); 1280 waves. k2/k3/k6 = R11.

#define NEGINF (-1e30f)

__device__ inline float waveRedSum(float v){
  #pragma unroll
  for (int o = 32; o > 0; o >>= 1) v += __shfl_down(v, o, 64);
  return v;
}
__device__ inline float waveRedMax(float v){
  #pragma unroll
  for (int o = 32; o > 0; o >>= 1) v = fmaxf(v, __shfl_down(v, o, 64));
  return v;
}
__device__ inline float4 f4z(){ return make_float4(0.f,0.f,0.f,0.f); }
#define F4C(v, c) ((c)==0?(v).x:(c)==1?(v).y:(c)==2?(v).z:(v).w)

// ================= K1: H = feat @ W^T + Wb  [4096 x 300], K=768 ====================
// 256 thr = 4 waves; wave w owns k in [w*192,(w+1)*192), kc=16, own LDS quadrant.
__global__ __launch_bounds__(256) void k1_h(const float* __restrict__ A,
                                            const float* __restrict__ W,
                                            const float* __restrict__ Wb,
                                            float* __restrict__ H){
  __shared__ float LSH[4][4352];        // per wave: staging As[0..1151] Bs[1152..2303]; combine 64x68
  const int fid = blockIdx.x;
  const int wl  = (fid & 7) * 40 + (fid >> 3);
  const int y = wl / 5, x = wl % 5;
  const int m0 = y * 64, c0 = x * 64;
  const int t = threadIdx.x;
  const int w = t >> 6, lane = t & 63;
  const int g = lane >> 3, h = lane & 7;
  float* As = &LSH[w][0];
  float* Bs = &LSH[w][1152];
  const int kw = w * 192;
  const bool bok = (c0 + lane) < 300;
  const float* Ap = A + (size_t)(m0 + lane) * 768 + kw;
  const float* Wp = W + (size_t)(c0 + lane) * 768 + kw;
  float4 a4[4], b4[4];
  float4 accL[8], accH[8];
  #pragma unroll
  for (int i = 0; i < 8; i++){ accL[i] = f4z(); accH[i] = f4z(); }
  #pragma unroll
  for (int j = 0; j < 4; j++){
    a4[j] = *(const float4*)(Ap + 4*j);
    b4[j] = bok ? *(const float4*)(Wp + 4*j) : f4z();
  }
  for (int tile = 0; tile < 12; ++tile){
    #pragma unroll
    for (int jj = 0; jj < 16; jj++){
      const int sw = (jj >> 2) & 3;
      const int pos = jj*72 + (((lane >> 2) ^ sw) << 2) + (lane & 3);
      As[pos] = F4C(a4[jj>>2], jj&3);
      Bs[pos] = F4C(b4[jj>>2], jj&3);
    }
    if (tile < 11){
      const int ofs = (tile + 1) * 16;
      #pragma unroll
      for (int j = 0; j < 4; j++){
        a4[j] = *(const float4*)(Ap + ofs + 4*j);
        b4[j] = bok ? *(const float4*)(Wp + ofs + 4*j) : f4z();
      }
    }
    #pragma unroll
    for (int kk = 0; kk < 16; kk++){
      const int sw = (kk >> 2) & 3;
      const float4 aL = *(const float4*)&As[kk*72 + (((2*g    ) ^ sw) << 2)];
      const float4 aH = *(const float4*)&As[kk*72 + (((2*g + 1) ^ sw) << 2)];
      const float4 bL = *(const float4*)&Bs[kk*72 + (((2*h    ) ^ sw) << 2)];
      const float4 bH = *(const float4*)&Bs[kk*72 + (((2*h + 1) ^ sw) << 2)];
      const float am[8] = {aL.x,aL.y,aL.z,aL.w,aH.x,aH.y,aH.z,aH.w};
      #pragma unroll
      for (int i = 0; i < 8; i++){
        accL[i].x += am[i]*bL.x; accL[i].y += am[i]*bL.y;
        accL[i].z += am[i]*bL.z; accL[i].w += am[i]*bL.w;
        accH[i].x += am[i]*bH.x; accH[i].y += am[i]*bH.y;
        accH[i].z += am[i]*bH.z; accH[i].w += am[i]*bH.w;
      }
    }
  }
  // combine: each wave dumps its 64x64 partial into its quadrant as [row][68]
  #pragma unroll
  for (int i = 0; i < 8; i++){
    const int r = g*8 + i;
    *(float4*)&LSH[w][r*68 + h*8    ] = accL[i];
    *(float4*)&LSH[w][r*68 + h*8 + 4] = accH[i];
  }
  __syncthreads();
  // wave w finalizes rows [w*16, w*16+16)
  const int rr = w*16 + (lane >> 2);
  const int cb = (lane & 3) * 16;
  #pragma unroll
  for (int c = 0; c < 16; c += 4){
    const int gcol = c0 + cb + c;
    if (gcol < 300){
      float4 s0 = *(float4*)&LSH[0][rr*68 + cb + c];
      float4 s1 = *(float4*)&LSH[1][rr*68 + cb + c];
      float4 s2 = *(float4*)&LSH[2][rr*68 + cb + c];
      float4 s3 = *(float4*)&LSH[3][rr*68 + cb + c];
      const float4 bi = *(const float4*)&Wb[gcol];
      float4 o = make_float4((s0.x+s1.x)+(s2.x+s3.x)+bi.x,
                             (s0.y+s1.y)+(s2.y+s3.y)+bi.y,
                             (s0.z+s1.z)+(s2.z+s3.z)+bi.z,
                             (s0.w+s1.w)+(s2.w+s3.w)+bi.w);
      *(float4*)&H[(size_t)(m0 + rr) * 300 + gcol] = o;
    }
  }
}

// ================= K2: S = H @ Bmat^T (+a1b cols<64)  [4096 x 128], K=300 ==========
__global__ __launch_bounds__(256) void k2_s(const float* __restrict__ Hm,
                                            const float* __restrict__ a1w,
                                            const float* __restrict__ a1b,
                                            float* __restrict__ S){
  __shared__ float As[2][32*40];
  __shared__ float Bs[2][32*136];
  const int bid = blockIdx.x;
  const int y = (bid & 7) * 16 + (bid >> 3);
  const int m0 = y * 32;
  const int t = threadIdx.x;
  const int tr4 = (t >> 5) * 4, tc = t & 31;
  const int arow = t >> 3, akq = t & 7;
  const int bn = t & 127, bkh = t >> 7;
  const float* brp = (bn < 64) ? &a1w[(size_t)bn * 600] : &a1w[(size_t)(bn - 64) * 600 + 300];
  float4 ha, b4[4];
  float4 acc[4];
  #pragma unroll
  for (int i = 0; i < 4; i++) acc[i] = f4z();
#define K2_LD(kt) { \
    const int ka = (kt) + akq*4; \
    ha = (ka < 300) ? *(const float4*)&Hm[(size_t)(m0 + arow)*300 + ka] : f4z(); \
    _Pragma("unroll") \
    for (int j = 0; j < 4; j++){ \
      const int kb = (kt) + bkh*16 + 4*j; \
      b4[j] = (kb < 300) ? *(const float4*)&brp[kb] : f4z(); \
    } }
  K2_LD(0)
  int p = 0;
  for (int tile = 0; tile < 10; ++tile){
    #pragma unroll
    for (int jj = 0; jj < 4; jj++)
      As[p][(akq*4 + jj)*40 + ((((arow>>2) ^ akq) & 7) << 2) + (arow & 3)] = F4C(ha, jj);
    #pragma unroll
    for (int jj = 0; jj < 16; jj++){
      const int kl = bkh*16 + jj;
      const int swb = (kl >> 2) & 7;
      Bs[p][kl*136 + (((bn>>2) ^ swb) << 2) + (bn & 3)] = F4C(b4[jj>>2], jj&3);
    }
    __syncthreads();
    if (tile < 9) K2_LD((tile + 1) * 32)
    #pragma unroll
    for (int kk = 0; kk < 32; kk++){
      const int sw = (kk >> 2) & 7;
      const float4 av = *(const float4*)&As[p][kk*40 + (((t>>5) ^ sw) << 2)];
      const float4 bv = *(const float4*)&Bs[p][kk*136 + ((tc ^ sw) << 2)];
      acc[0].x += av.x*bv.x; acc[0].y += av.x*bv.y; acc[0].z += av.x*bv.z; acc[0].w += av.x*bv.w;
      acc[1].x += av.y*bv.x; acc[1].y += av.y*bv.y; acc[1].z += av.y*bv.z; acc[1].w += av.y*bv.w;
      acc[2].x += av.z*bv.x; acc[2].y += av.z*bv.y; acc[2].z += av.z*bv.z; acc[2].w += av.z*bv.w;
      acc[3].x += av.w*bv.x; acc[3].y += av.w*bv.y; acc[3].z += av.w*bv.z; acc[3].w += av.w*bv.w;
    }
    p ^= 1;
  }
#undef K2_LD
  const int tc4 = tc * 4;
  float4 bi = f4z();
  if (tc4 < 64) bi = *(const float4*)&a1b[tc4];
  #pragma unroll
  for (int i = 0; i < 4; i++){
    float4 o = make_float4(acc[i].x+bi.x, acc[i].y+bi.y, acc[i].z+bi.z, acc[i].w+bi.w);
    *(float4*)&S[(size_t)(m0 + tr4 + i) * 128 + tc4] = o;
  }
}

// ================= K3: logits + mask + per-block (max, sum-exp) =====================
__global__ __launch_bounds__(256) void k3_logits(const float* __restrict__ S,
                                                 const float* __restrict__ adj,
                                                 const float* __restrict__ a2w,
                                                 const float* __restrict__ a2b,
                                                 float* __restrict__ L,
                                                 float* __restrict__ bm,
                                                 float* __restrict__ bs){
  __shared__ float si_s[32*68];
  __shared__ float sj_s[64*68];
  __shared__ float w_s[64];
  __shared__ float redm[4];
  __shared__ float reds[4];
  __shared__ float smax;
  const int b  = blockIdx.z;
  const int i0 = blockIdx.y * 32;
  const int j0 = blockIdx.x * 64;
  const int t  = threadIdx.x;
  if (t < 16) *(float4*)&w_s[t*4] = *(const float4*)&a2w[t*4];
  #pragma unroll
  for (int q = 0; q < 2; q++){
    int c = t + q*256; int r = c >> 4, c4 = c & 15;
    *(float4*)&si_s[r*68 + c4*4] = *(const float4*)&S[(size_t)(b*512 + i0 + r)*128 + c4*4];
  }
  #pragma unroll
  for (int q = 0; q < 4; q++){
    int c = t + q*256; int r = c >> 4, c4 = c & 15;
    *(float4*)&sj_s[r*68 + c4*4] = *(const float4*)&S[(size_t)(b*512 + j0 + r)*128 + 64 + c4*4];
  }
  __syncthreads();
  const int j = t & 63, iq = t >> 6;
  const float a2bv = a2b[0];
  float4 acc[8];
  #pragma unroll
  for (int ii = 0; ii < 8; ii++) acc[ii] = f4z();
  #pragma unroll
  for (int k4 = 0; k4 < 16; k4++){
    const float4 sj4 = *(const float4*)&sj_s[j*68 + k4*4];
    const float4 w4  = *(const float4*)&w_s[k4*4];
    #pragma unroll
    for (int ii = 0; ii < 8; ii++){
      const int i = ii*4 + iq;                 // wave-uniform -> LDS broadcast
      const float4 si4 = *(const float4*)&si_s[i*68 + k4*4];
      acc[ii].x += fmaxf(si4.x + sj4.x, 0.f) * w4.x;
      acc[ii].y += fmaxf(si4.y + sj4.y, 0.f) * w4.y;
      acc[ii].z += fmaxf(si4.z + sj4.z, 0.f) * w4.z;
      acc[ii].w += fmaxf(si4.w + sj4.w, 0.f) * w4.w;
    }
  }
  float l_arr[8];
  float locmax = -3e38f;
  #pragma unroll
  for (int ii = 0; ii < 8; ii++){
    const int i = ii*4 + iq;
    float e = ((acc[ii].x + acc[ii].y) + (acc[ii].z + acc[ii].w)) + a2bv;
    e = (e >= 0.f) ? e : 0.01f * e;
    size_t idxg = (size_t)(b*512 + i0 + i)*512 + j0 + j;
    float l = (adj[idxg] != 0.f) ? e : NEGINF;
    l_arr[ii] = l;
    L[idxg] = l;
    locmax = fmaxf(locmax, l);
  }
  float m = waveRedMax(locmax);
  if ((t & 63) == 0) redm[t >> 6] = m;
  __syncthreads();
  if (t == 0) smax = fmaxf(fmaxf(redm[0], redm[1]), fmaxf(redm[2], redm[3]));
  __syncthreads();
  const float mb = smax;
  float sacc = 0.f;
  #pragma unroll
  for (int ii = 0; ii < 8; ii++) sacc += __expf(l_arr[ii] - mb);
  sacc = waveRedSum(sacc);
  if ((t & 63) == 0) reds[t >> 6] = sacc;
  __syncthreads();
  if (t == 0){
    const int bid = (blockIdx.z * 16 + blockIdx.y) * 8 + blockIdx.x;
    bm[bid] = mb;
    bs[bid] = (reds[0] + reds[1]) + (reds[2] + reds[3]);
  }
}

// ================= K6: combine per-block (m,s) -> per-batch (maxg, sums) ============
__global__ __launch_bounds__(128) void k6_red(const float* __restrict__ bm,
                                              const float* __restrict__ bs,
                                              float* __restrict__ sums,
                                              float* __restrict__ maxg){
  const int b = blockIdx.x, t = threadIdx.x;
  const float m = bm[b*128 + t];
  float mm = waveRedMax(m);
  __shared__ float r2m[2];
  __shared__ float mgs;
  if ((t & 63) == 0) r2m[t >> 6] = mm;
  __syncthreads();
  if (t == 0) mgs = fmaxf(r2m[0], r2m[1]);
  __syncthreads();
  const float mg = mgs;
  float v = bs[b*128 + t] * __expf(m - mg);
  v = waveRedSum(v);
  __shared__ float r2s[2];
  if ((t & 63) == 0) r2s[t >> 6] = v;
  __syncthreads();
  if (t == 0){ sums[b] = r2s[0] + r2s[1]; maxg[b] = mg; }
}

// ================= K7: out = (exp(L-maxg) @ H) / sums; per-batch [512x300] ==========
// 256 thr = 4 waves; wave w owns k in [w*128,(w+1)*128), kc=16. Same combine as k1.
__global__ __launch_bounds__(256) void k7_out(const float* __restrict__ Lr,
                                              const float* __restrict__ Hm,
                                              const float* __restrict__ sums,
                                              const float* __restrict__ maxg,
                                              float* __restrict__ out){
  __shared__ float LSH[4][4352];
  const int fid = blockIdx.x;
  const int b  = fid & 7;
  const int idx = fid >> 3;
  const int y = idx / 5, x = idx % 5;
  const int m0 = y * 64, c0 = x * 64;
  const int t = threadIdx.x;
  const int w = t >> 6, lane = t & 63;
  const int g = lane >> 3, h = lane & 7;
  float* As = &LSH[w][0];
  float* Bs = &LSH[w][1152];
  const int kw = w * 128;
  const float mx = maxg[b];
  const float* Lp = Lr + (size_t)(b*512 + m0 + lane) * 512 + kw;
  const float* Hb = Hm + (size_t)(b*512) * 300;
  const int kr = lane >> 2, cq = lane & 3;    // B staging: k-row 0..15, col-quarter
  float4 a4[4], b4[4];
  float4 accL[8], accH[8];
  #pragma unroll
  for (int i = 0; i < 8; i++){ accL[i] = f4z(); accH[i] = f4z(); }
#define K7_LDB(kt) { \
    const float* hr = Hb + (size_t)((kt) + kr) * 300; \
    _Pragma("unroll") \
    for (int j = 0; j < 4; j++){ \
      const int colj = c0 + cq*16 + 4*j; \
      b4[j] = (colj < 300) ? *(const float4*)&hr[colj] : f4z(); \
    } }
  #pragma unroll
  for (int j = 0; j < 4; j++) a4[j] = *(const float4*)(Lp + 4*j);
  K7_LDB(kw)
  for (int tile = 0; tile < 8; ++tile){
    #pragma unroll
    for (int jj = 0; jj < 16; jj++){
      const int sw = (jj >> 2) & 3;
      As[jj*72 + (((lane >> 2) ^ sw) << 2) + (lane & 3)] = __expf(F4C(a4[jj>>2], jj&3) - mx);
    }
    {
      const int swb = (kr >> 2) & 3;
      #pragma unroll
      for (int j = 0; j < 4; j++)
        *(float4*)&Bs[kr*72 + (((cq*4 + j) ^ swb) << 2)] = b4[j];
    }
    if (tile < 7){
      const int ofs = (tile + 1) * 16;
      #pragma unroll
      for (int j = 0; j < 4; j++) a4[j] = *(const float4*)(Lp + ofs + 4*j);
      K7_LDB(kw + ofs)
    }
    #pragma unroll
    for (int kk = 0; kk < 16; kk++){
      const int sw = (kk >> 2) & 3;
      const float4 aL = *(const float4*)&As[kk*72 + (((2*g    ) ^ sw) << 2)];
      const float4 aH = *(const float4*)&As[kk*72 + (((2*g + 1) ^ sw) << 2)];
      const float4 bL = *(const float4*)&Bs[kk*72 + (((2*h    ) ^ sw) << 2)];
      const float4 bH = *(const float4*)&Bs[kk*72 + (((2*h + 1) ^ sw) << 2)];
      const float am[8] = {aL.x,aL.y,aL.z,aL.w,aH.x,aH.y,aH.z,aH.w};
      #pragma unroll
      for (int i = 0; i < 8; i++){
        accL[i].x += am[i]*bL.x; accL[i].y += am[i]*bL.y;
        accL[i].z += am[i]*bL.z; accL[i].w += am[i]*bL.w;
        accH[i].x += am[i]*bH.x; accH[i].y += am[i]*bH.y;
        accH[i].z += am[i]*bH.z; accH[i].w += am[i]*bH.w;
      }
    }
  }
#undef K7_LDB
  #pragma unroll
  for (int i = 0; i < 8; i++){
    const int r = g*8 + i;
    *(float4*)&LSH[w][r*68 + h*8    ] = accL[i];
    *(float4*)&LSH[w][r*68 + h*8 + 4] = accH[i];
  }
  __syncthreads();
  const int rr = w*16 + (lane >> 2);
  const int cb = (lane & 3) * 16;
  const float invs = 1.0f / sums[b];
  #pragma unroll
  for (int c = 0; c < 16; c += 4){
    const int gcol = c0 + cb + c;
    if (gcol < 300){
      float4 s0 = *(float4*)&LSH[0][rr*68 + cb + c];
      float4 s1 = *(float4*)&LSH[1][rr*68 + cb + c];
      float4 s2 = *(float4*)&LSH[2][rr*68 + cb + c];
      float4 s3 = *(float4*)&LSH[3][rr*68 + cb + c];
      float4 o = make_float4(((s0.x+s1.x)+(s2.x+s3.x))*invs,
                             ((s0.y+s1.y)+(s2.y+s3.y))*invs,
                             ((s0.z+s1.z)+(s2.z+s3.z))*invs,
                             ((s0.w+s1.w)+(s2.w+s3.w))*invs);
      *(float4*)&out[(size_t)(b*512 + m0 + rr) * 300 + gcol] = o;
    }
  }
}

extern "C" void kernel_launch(void* const* d_in, const int* in_sizes, int n_in,
                              void* d_out, int out_size, void* d_ws, size_t ws_size,
                              hipStream_t stream){
  const float* adj  = (const float*)d_in[0];
  const float* feat = (const float*)d_in[1];
  const float* Ww   = (const float*)d_in[2];
  const float* Wb   = (const float*)d_in[3];
  const float* a1w  = (const float*)d_in[4];
  const float* a1b  = (const float*)d_in[5];
  const float* a2w  = (const float*)d_in[6];
  const float* a2b  = (const float*)d_in[7];
  float* out = (float*)d_out;
  char* ws = (char*)d_ws;

  float* H    = (float*)(ws + 0);           // 4,915,200 B
  float* S    = (float*)(ws + 4915200);     // 2,097,152 B
  float* L    = (float*)(ws + 7012352);     // 8,388,608 B
  float* bm   = (float*)(ws + 15400960);    // 4,096 B
  float* bs   = (float*)(ws + 15405056);    // 4,096 B
  float* sums = (float*)(ws + 15409152);    // 32 B
  float* maxg = (float*)(ws + 15409216);    // 32 B

  k1_h     <<<dim3(320),      dim3(256), 0, stream>>>(feat, Ww, Wb, H);
  k2_s     <<<dim3(128),      dim3(256), 0, stream>>>(H, a1w, a1b, S);
  k3_logits<<<dim3(8, 16, 8), dim3(256), 0, stream>>>(S, adj, a2w, a2b, L, bm, bs);
  k6_red   <<<dim3(8),        dim3(128), 0, stream>>>(bm, bs, sums, maxg);
  k7_out   <<<dim3(320),      dim3(256), 0, stream>>>(L, H, sums, maxg, out);
}

// Round 13
// 144.272 us; speedup vs baseline: 1.3945x; 1.0614x over previous
//
#include <hip/hip_runtime.h>
// R13: k1/k7 -> 8-wave (512thr) in-block split-K, per-wave private single-buffer
// swizzled LDS (no main-loop barriers), LDS 73.7KB (combine tree overlaid on
// staging), coalesced staging loads (16 lines/instr not 64). k2/k3/k6 = R11.

#define NEGINF (-1e30f)

__device__ inline float waveRedSum(float v){
  #pragma unroll
  for (int o = 32; o > 0; o >>= 1) v += __shfl_down(v, o, 64);
  return v;
}
__device__ inline float waveRedMax(float v){
  #pragma unroll
  for (int o = 32; o > 0; o >>= 1) v = fmaxf(v, __shfl_down(v, o, 64));
  return v;
}
__device__ inline float4 f4z(){ return make_float4(0.f,0.f,0.f,0.f); }
#define F4C(v, c) ((c)==0?(v).x:(c)==1?(v).y:(c)==2?(v).z:(v).w)

__device__ inline void dumpP(float* buf, const float4* accL, const float4* accH,
                             int g, int h){
  #pragma unroll
  for (int i = 0; i < 8; i++){
    const int r = g*8 + i;
    *(float4*)&buf[r*68 + h*8    ] = accL[i];
    *(float4*)&buf[r*68 + h*8 + 4] = accH[i];
  }
}
__device__ inline void addP(const float* buf, float4* accL, float4* accH,
                            int g, int h){
  #pragma unroll
  for (int i = 0; i < 8; i++){
    const int r = g*8 + i;
    const float4 u = *(const float4*)&buf[r*68 + h*8];
    const float4 v = *(const float4*)&buf[r*68 + h*8 + 4];
    accL[i].x += u.x; accL[i].y += u.y; accL[i].z += u.z; accL[i].w += u.w;
    accH[i].x += v.x; accH[i].y += v.y; accH[i].z += v.z; accH[i].w += v.w;
  }
}

// ================= K1: H = feat @ W^T + Wb  [4096 x 300], K=768 ====================
// 512 thr = 8 waves, split-K=8 (96 k/wave), tile 64x64, 8x8 acc, kc=16.
__global__ __launch_bounds__(512) void k1_h(const float* __restrict__ A,
                                            const float* __restrict__ W,
                                            const float* __restrict__ Wb,
                                            float* __restrict__ H){
  __shared__ float LSH[8][2304];
  float* CB = &LSH[0][0];
  const int fid = blockIdx.x;
  const int wl  = (fid & 7) * 40 + (fid >> 3);
  const int y = wl / 5, x = wl % 5;
  const int m0 = y * 64, c0 = x * 64;
  const int t = threadIdx.x;
  const int w = t >> 6, lane = t & 63;
  const int g = lane >> 3, h = lane & 7;
  const int lr = lane >> 2, lk = lane & 3;
  float* As = &LSH[w][0];
  float* Bs = &LSH[w][1152];
  const int kw = w * 96;
  float4 a4[4], b4[4], accL[8], accH[8];
  #pragma unroll
  for (int i = 0; i < 8; i++){ accL[i] = f4z(); accH[i] = f4z(); }
#define K1_LD(kt) { _Pragma("unroll") \
  for (int q = 0; q < 4; q++){ \
    const int row = lr + 16*q; \
    a4[q] = *(const float4*)&A[(size_t)(m0 + row)*768 + (kt) + lk*4]; \
    b4[q] = (c0 + row < 300) ? *(const float4*)&W[(size_t)(c0 + row)*768 + (kt) + lk*4] : f4z(); } }
  K1_LD(kw)
  for (int tile = 0; tile < 6; ++tile){
    #pragma unroll
    for (int q = 0; q < 4; q++){
      const int rpos = ((((lr >> 2) + 4*q) ^ lk) << 2) | (lr & 3);
      #pragma unroll
      for (int j = 0; j < 4; j++){
        As[(lk*4 + j)*72 + rpos] = F4C(a4[q], j);
        Bs[(lk*4 + j)*72 + rpos] = F4C(b4[q], j);
      }
    }
    if (tile < 5) K1_LD(kw + (tile + 1) * 16)
    #pragma unroll
    for (int kk = 0; kk < 16; kk++){
      const int sw = (kk >> 2) & 3;
      const float4 aL = *(const float4*)&As[kk*72 + (((2*g    ) ^ sw) << 2)];
      const float4 aH = *(const float4*)&As[kk*72 + (((2*g + 1) ^ sw) << 2)];
      const float4 bL = *(const float4*)&Bs[kk*72 + (((2*h    ) ^ sw) << 2)];
      const float4 bH = *(const float4*)&Bs[kk*72 + (((2*h + 1) ^ sw) << 2)];
      const float am[8] = {aL.x,aL.y,aL.z,aL.w,aH.x,aH.y,aH.z,aH.w};
      #pragma unroll
      for (int i = 0; i < 8; i++){
        accL[i].x += am[i]*bL.x; accL[i].y += am[i]*bL.y;
        accL[i].z += am[i]*bL.z; accL[i].w += am[i]*bL.w;
        accH[i].x += am[i]*bH.x; accH[i].y += am[i]*bH.y;
        accH[i].z += am[i]*bH.z; accH[i].w += am[i]*bH.w;
      }
    }
  }
#undef K1_LD
  // tree combine 8 -> 4 -> 2, overlaid on staging LDS
  __syncthreads();
  if (w >= 4) dumpP(CB + (w - 4)*4352, accL, accH, g, h);
  __syncthreads();
  if (w < 4) addP(CB + w*4352, accL, accH, g, h);
  __syncthreads();
  if (w == 2 || w == 3) dumpP(CB + (w - 2)*4352, accL, accH, g, h);
  __syncthreads();
  if (w < 2){ addP(CB + w*4352, accL, accH, g, h); dumpP(CB + w*4352, accL, accH, g, h); }
  __syncthreads();
  // finalize: all 512 threads
  const int fr = t >> 3, fc = (t & 7) * 8;
  const int gcol = c0 + fc;
  const float4* p0 = (const float4*)&CB[fr*68 + fc];
  const float4* p1 = (const float4*)&CB[4352 + fr*68 + fc];
  if (gcol < 300){
    const float4 u = p0[0], v = p1[0];
    const float4 bi = *(const float4*)&Wb[gcol];
    *(float4*)&H[(size_t)(m0 + fr)*300 + gcol] =
      make_float4(u.x+v.x+bi.x, u.y+v.y+bi.y, u.z+v.z+bi.z, u.w+v.w+bi.w);
  }
  if (gcol + 4 < 300){
    const float4 u = p0[1], v = p1[1];
    const float4 bi = *(const float4*)&Wb[gcol + 4];
    *(float4*)&H[(size_t)(m0 + fr)*300 + gcol + 4] =
      make_float4(u.x+v.x+bi.x, u.y+v.y+bi.y, u.z+v.z+bi.z, u.w+v.w+bi.w);
  }
}

// ================= K2: S = H @ Bmat^T (+a1b cols<64)  [4096 x 128], K=300 ==========
__global__ __launch_bounds__(256) void k2_s(const float* __restrict__ Hm,
                                            const float* __restrict__ a1w,
                                            const float* __restrict__ a1b,
                                            float* __restrict__ S){
  __shared__ float As[2][32*40];
  __shared__ float Bs[2][32*136];
  const int bid = blockIdx.x;
  const int y = (bid & 7) * 16 + (bid >> 3);
  const int m0 = y * 32;
  const int t = threadIdx.x;
  const int tr4 = (t >> 5) * 4, tc = t & 31;
  const int arow = t >> 3, akq = t & 7;
  const int bn = t & 127, bkh = t >> 7;
  const float* brp = (bn < 64) ? &a1w[(size_t)bn * 600] : &a1w[(size_t)(bn - 64) * 600 + 300];
  float4 ha, b4[4];
  float4 acc[4];
  #pragma unroll
  for (int i = 0; i < 4; i++) acc[i] = f4z();
#define K2_LD(kt) { \
    const int ka = (kt) + akq*4; \
    ha = (ka < 300) ? *(const float4*)&Hm[(size_t)(m0 + arow)*300 + ka] : f4z(); \
    _Pragma("unroll") \
    for (int j = 0; j < 4; j++){ \
      const int kb = (kt) + bkh*16 + 4*j; \
      b4[j] = (kb < 300) ? *(const float4*)&brp[kb] : f4z(); \
    } }
  K2_LD(0)
  int p = 0;
  for (int tile = 0; tile < 10; ++tile){
    #pragma unroll
    for (int jj = 0; jj < 4; jj++)
      As[p][(akq*4 + jj)*40 + ((((arow>>2) ^ akq) & 7) << 2) + (arow & 3)] = F4C(ha, jj);
    #pragma unroll
    for (int jj = 0; jj < 16; jj++){
      const int kl = bkh*16 + jj;
      const int swb = (kl >> 2) & 7;
      Bs[p][kl*136 + (((bn>>2) ^ swb) << 2) + (bn & 3)] = F4C(b4[jj>>2], jj&3);
    }
    __syncthreads();
    if (tile < 9) K2_LD((tile + 1) * 32)
    #pragma unroll
    for (int kk = 0; kk < 32; kk++){
      const int sw = (kk >> 2) & 7;
      const float4 av = *(const float4*)&As[p][kk*40 + (((t>>5) ^ sw) << 2)];
      const float4 bv = *(const float4*)&Bs[p][kk*136 + ((tc ^ sw) << 2)];
      acc[0].x += av.x*bv.x; acc[0].y += av.x*bv.y; acc[0].z += av.x*bv.z; acc[0].w += av.x*bv.w;
      acc[1].x += av.y*bv.x; acc[1].y += av.y*bv.y; acc[1].z += av.y*bv.z; acc[1].w += av.y*bv.w;
      acc[2].x += av.z*bv.x; acc[2].y += av.z*bv.y; acc[2].z += av.z*bv.z; acc[2].w += av.z*bv.w;
      acc[3].x += av.w*bv.x; acc[3].y += av.w*bv.y; acc[3].z += av.w*bv.z; acc[3].w += av.w*bv.w;
    }
    p ^= 1;
  }
#undef K2_LD
  const int tc4 = tc * 4;
  float4 bi = f4z();
  if (tc4 < 64) bi = *(const float4*)&a1b[tc4];
  #pragma unroll
  for (int i = 0; i < 4; i++){
    float4 o = make_float4(acc[i].x+bi.x, acc[i].y+bi.y, acc[i].z+bi.z, acc[i].w+bi.w);
    *(float4*)&S[(size_t)(m0 + tr4 + i) * 128 + tc4] = o;
  }
}

// ================= K3: logits + mask + per-block (max, sum-exp) =====================
__global__ __launch_bounds__(256) void k3_logits(const float* __restrict__ S,
                                                 const float* __restrict__ adj,
                                                 const float* __restrict__ a2w,
                                                 const float* __restrict__ a2b,
                                                 float* __restrict__ L,
                                                 float* __restrict__ bm,
                                                 float* __restrict__ bs){
  __shared__ float si_s[32*68];
  __shared__ float sj_s[64*68];
  __shared__ float w_s[64];
  __shared__ float redm[4];
  __shared__ float reds[4];
  __shared__ float smax;
  const int b  = blockIdx.z;
  const int i0 = blockIdx.y * 32;
  const int j0 = blockIdx.x * 64;
  const int t  = threadIdx.x;
  if (t < 16) *(float4*)&w_s[t*4] = *(const float4*)&a2w[t*4];
  #pragma unroll
  for (int q = 0; q < 2; q++){
    int c = t + q*256; int r = c >> 4, c4 = c & 15;
    *(float4*)&si_s[r*68 + c4*4] = *(const float4*)&S[(size_t)(b*512 + i0 + r)*128 + c4*4];
  }
  #pragma unroll
  for (int q = 0; q < 4; q++){
    int c = t + q*256; int r = c >> 4, c4 = c & 15;
    *(float4*)&sj_s[r*68 + c4*4] = *(const float4*)&S[(size_t)(b*512 + j0 + r)*128 + 64 + c4*4];
  }
  __syncthreads();
  const int j = t & 63, iq = t >> 6;
  const float a2bv = a2b[0];
  float4 acc[8];
  #pragma unroll
  for (int ii = 0; ii < 8; ii++) acc[ii] = f4z();
  #pragma unroll
  for (int k4 = 0; k4 < 16; k4++){
    const float4 sj4 = *(const float4*)&sj_s[j*68 + k4*4];
    const float4 w4  = *(const float4*)&w_s[k4*4];
    #pragma unroll
    for (int ii = 0; ii < 8; ii++){
      const int i = ii*4 + iq;
      const float4 si4 = *(const float4*)&si_s[i*68 + k4*4];
      acc[ii].x += fmaxf(si4.x + sj4.x, 0.f) * w4.x;
      acc[ii].y += fmaxf(si4.y + sj4.y, 0.f) * w4.y;
      acc[ii].z += fmaxf(si4.z + sj4.z, 0.f) * w4.z;
      acc[ii].w += fmaxf(si4.w + sj4.w, 0.f) * w4.w;
    }
  }
  float l_arr[8];
  float locmax = -3e38f;
  #pragma unroll
  for (int ii = 0; ii < 8; ii++){
    const int i = ii*4 + iq;
    float e = ((acc[ii].x + acc[ii].y) + (acc[ii].z + acc[ii].w)) + a2bv;
    e = (e >= 0.f) ? e : 0.01f * e;
    size_t idxg = (size_t)(b*512 + i0 + i)*512 + j0 + j;
    float l = (adj[idxg] != 0.f) ? e : NEGINF;
    l_arr[ii] = l;
    L[idxg] = l;
    locmax = fmaxf(locmax, l);
  }
  float m = waveRedMax(locmax);
  if ((t & 63) == 0) redm[t >> 6] = m;
  __syncthreads();
  if (t == 0) smax = fmaxf(fmaxf(redm[0], redm[1]), fmaxf(redm[2], redm[3]));
  __syncthreads();
  const float mb = smax;
  float sacc = 0.f;
  #pragma unroll
  for (int ii = 0; ii < 8; ii++) sacc += __expf(l_arr[ii] - mb);
  sacc = waveRedSum(sacc);
  if ((t & 63) == 0) reds[t >> 6] = sacc;
  __syncthreads();
  if (t == 0){
    const int bid = (blockIdx.z * 16 + blockIdx.y) * 8 + blockIdx.x;
    bm[bid] = mb;
    bs[bid] = (reds[0] + reds[1]) + (reds[2] + reds[3]);
  }
}

// ================= K6: combine per-block (m,s) -> per-batch (maxg, sums) ============
__global__ __launch_bounds__(128) void k6_red(const float* __restrict__ bm,
                                              const float* __restrict__ bs,
                                              float* __restrict__ sums,
                                              float* __restrict__ maxg){
  const int b = blockIdx.x, t = threadIdx.x;
  const float m = bm[b*128 + t];
  float mm = waveRedMax(m);
  __shared__ float r2m[2];
  __shared__ float mgs;
  if ((t & 63) == 0) r2m[t >> 6] = mm;
  __syncthreads();
  if (t == 0) mgs = fmaxf(r2m[0], r2m[1]);
  __syncthreads();
  const float mg = mgs;
  float v = bs[b*128 + t] * __expf(m - mg);
  v = waveRedSum(v);
  __shared__ float r2s[2];
  if ((t & 63) == 0) r2s[t >> 6] = v;
  __syncthreads();
  if (t == 0){ sums[b] = r2s[0] + r2s[1]; maxg[b] = mg; }
}

// ================= K7: out = (exp(L-maxg) @ H) / sums; per-batch [512x300] ==========
// 512 thr = 8 waves, split-K=8 (64 k/wave), tile 64x64, 8x8 acc, kc=16.
__global__ __launch_bounds__(512) void k7_out(const float* __restrict__ Lr,
                                              const float* __restrict__ Hm,
                                              const float* __restrict__ sums,
                                              const float* __restrict__ maxg,
                                              float* __restrict__ out){
  __shared__ float LSH[8][2304];
  float* CB = &LSH[0][0];
  const int fid = blockIdx.x;
  const int b  = fid & 7;
  const int idx = fid >> 3;
  const int y = idx / 5, x = idx % 5;
  const int m0 = y * 64, c0 = x * 64;
  const int t = threadIdx.x;
  const int w = t >> 6, lane = t & 63;
  const int g = lane >> 3, h = lane & 7;
  const int lr = lane >> 2, lk = lane & 3;
  const int kr = lane >> 2, cq = lane & 3;
  float* As = &LSH[w][0];
  float* Bs = &LSH[w][1152];
  const int kw = w * 64;
  const float mx = maxg[b];
  const float* Hb = Hm + (size_t)(b*512) * 300;
  float4 a4[4], b4[4], accL[8], accH[8];
  #pragma unroll
  for (int i = 0; i < 8; i++){ accL[i] = f4z(); accH[i] = f4z(); }
#define K7_LDA(kt) { _Pragma("unroll") \
  for (int q = 0; q < 4; q++){ \
    const int row = lr + 16*q; \
    a4[q] = *(const float4*)&Lr[(size_t)(b*512 + m0 + row)*512 + (kt) + lk*4]; } }
#define K7_LDB(kt) { \
    const float* hr = Hb + (size_t)((kt) + kr) * 300; \
    _Pragma("unroll") \
    for (int j = 0; j < 4; j++){ \
      const int colj = c0 + cq*16 + 4*j; \
      b4[j] = (colj < 300) ? *(const float4*)&hr[colj] : f4z(); } }
  K7_LDA(kw)
  K7_LDB(kw)
  for (int tile = 0; tile < 4; ++tile){
    #pragma unroll
    for (int q = 0; q < 4; q++){
      const int rpos = ((((lr >> 2) + 4*q) ^ lk) << 2) | (lr & 3);
      #pragma unroll
      for (int j = 0; j < 4; j++)
        As[(lk*4 + j)*72 + rpos] = __expf(F4C(a4[q], j) - mx);
    }
    {
      const int swb = (kr >> 2) & 3;
      #pragma unroll
      for (int j = 0; j < 4; j++)
        *(float4*)&Bs[kr*72 + (((cq*4 + j) ^ swb) << 2)] = b4[j];
    }
    if (tile < 3){
      const int ofs = kw + (tile + 1) * 16;
      K7_LDA(ofs)
      K7_LDB(ofs)
    }
    #pragma unroll
    for (int kk = 0; kk < 16; kk++){
      const int sw = (kk >> 2) & 3;
      const float4 aL = *(const float4*)&As[kk*72 + (((2*g    ) ^ sw) << 2)];
      const float4 aH = *(const float4*)&As[kk*72 + (((2*g + 1) ^ sw) << 2)];
      const float4 bL = *(const float4*)&Bs[kk*72 + (((2*h    ) ^ sw) << 2)];
      const float4 bH = *(const float4*)&Bs[kk*72 + (((2*h + 1) ^ sw) << 2)];
      const float am[8] = {aL.x,aL.y,aL.z,aL.w,aH.x,aH.y,aH.z,aH.w};
      #pragma unroll
      for (int i = 0; i < 8; i++){
        accL[i].x += am[i]*bL.x; accL[i].y += am[i]*bL.y;
        accL[i].z += am[i]*bL.z; accL[i].w += am[i]*bL.w;
        accH[i].x += am[i]*bH.x; accH[i].y += am[i]*bH.y;
        accH[i].z += am[i]*bH.z; accH[i].w += am[i]*bH.w;
      }
    }
  }
#undef K7_LDA
#undef K7_LDB
  __syncthreads();
  if (w >= 4) dumpP(CB + (w - 4)*4352, accL, accH, g, h);
  __syncthreads();
  if (w < 4) addP(CB + w*4352, accL, accH, g, h);
  __syncthreads();
  if (w == 2 || w == 3) dumpP(CB + (w - 2)*4352, accL, accH, g, h);
  __syncthreads();
  if (w < 2){ addP(CB + w*4352, accL, accH, g, h); dumpP(CB + w*4352, accL, accH, g, h); }
  __syncthreads();
  const float invs = 1.0f / sums[b];
  const int fr = t >> 3, fc = (t & 7) * 8;
  const int gcol = c0 + fc;
  const float4* p0 = (const float4*)&CB[fr*68 + fc];
  const float4* p1 = (const float4*)&CB[4352 + fr*68 + fc];
  if (gcol < 300){
    const float4 u = p0[0], v = p1[0];
    *(float4*)&out[(size_t)(b*512 + m0 + fr)*300 + gcol] =
      make_float4((u.x+v.x)*invs, (u.y+v.y)*invs, (u.z+v.z)*invs, (u.w+v.w)*invs);
  }
  if (gcol + 4 < 300){
    const float4 u = p0[1], v = p1[1];
    *(float4*)&out[(size_t)(b*512 + m0 + fr)*300 + gcol + 4] =
      make_float4((u.x+v.x)*invs, (u.y+v.y)*invs, (u.z+v.z)*invs, (u.w+v.w)*invs);
  }
}

extern "C" void kernel_launch(void* const* d_in, const int* in_sizes, int n_in,
                              void* d_out, int out_size, void* d_ws, size_t ws_size,
                              hipStream_t stream){
  const float* adj  = (const float*)d_in[0];
  const float* feat = (const float*)d_in[1];
  const float* Ww   = (const float*)d_in[2];
  const float* Wb   = (const float*)d_in[3];
  const float* a1w  = (const float*)d_in[4];
  const float* a1b  = (const float*)d_in[5];
  const float* a2w  = (const float*)d_in[6];
  const float* a2b  = (const float*)d_in[7];
  float* out = (float*)d_out;
  char* ws = (char*)d_ws;

  float* H    = (float*)(ws + 0);           // 4,915,200 B
  float* S    = (float*)(ws + 4915200);     // 2,097,152 B
  float* L    = (float*)(ws + 7012352);     // 8,388,608 B
  float* bm   = (float*)(ws + 15400960);    // 4,096 B
  float* bs   = (float*)(ws + 15405056);    // 4,096 B
  float* sums = (float*)(ws + 15409152);    // 32 B
  float* maxg = (float*)(ws + 15409216);    // 32 B

  k1_h     <<<dim3(320),      dim3(512), 0, stream>>>(feat, Ww, Wb, H);
  k2_s     <<<dim3(128),      dim3(256), 0, stream>>>(H, a1w, a1b, S);
  k3_logits<<<dim3(8, 16, 8), dim3(256), 0, stream>>>(S, adj, a2w, a2b, L, bm, bs);
  k6_red   <<<dim3(8),        dim3(128), 0, stream>>>(bm, bs, sums, maxg);
  k7_out   <<<dim3(320),      dim3(512), 0, stream>>>(L, H, sums, maxg, out);
}

// Round 14
// 119.289 us; speedup vs baseline: 1.6866x; 1.2094x over previous
//
#include <hip/hip_runtime.h>
// R14: k1 -> MFMA split-bf16 (3-mfma fp32 emulation, rel err ~4e-6).
// 256thr/4-wave, 64x64 tile, wave=32x32 (2x2 frags), LDS [64][40]bf16 hi/lo.
// k2/k3/k6/k7 byte-identical to R13 (pilot: one variable).

#define NEGINF (-1e30f)

typedef __attribute__((ext_vector_type(8))) short short8;
typedef __attribute__((ext_vector_type(4))) float f32x4;

__device__ inline float waveRedSum(float v){
  #pragma unroll
  for (int o = 32; o > 0; o >>= 1) v += __shfl_down(v, o, 64);
  return v;
}
__device__ inline float waveRedMax(float v){
  #pragma unroll
  for (int o = 32; o > 0; o >>= 1) v = fmaxf(v, __shfl_down(v, o, 64));
  return v;
}
__device__ inline float4 f4z(){ return make_float4(0.f,0.f,0.f,0.f); }
#define F4C(v, c) ((c)==0?(v).x:(c)==1?(v).y:(c)==2?(v).z:(v).w)

__device__ inline unsigned short f2bf(float f){
  unsigned u = __float_as_uint(f);
  unsigned r = u + 0x7fffu + ((u >> 16) & 1u);
  return (unsigned short)(r >> 16);
}
__device__ inline float bf2f(unsigned short h){
  return __uint_as_float(((unsigned)h) << 16);
}

// ================= K1: H = feat @ W^T + Wb  [4096 x 300], K=768, MFMA ==============
// grid 320 (8 XCD-chunks x 40), 256 thr = 4 waves (2x2), 24 k-tiles of 32.
__global__ __launch_bounds__(256) void k1_h(const float* __restrict__ A,
                                            const float* __restrict__ W,
                                            const float* __restrict__ Wb,
                                            float* __restrict__ H){
  __shared__ short Ah[2][64*40];
  __shared__ short Al[2][64*40];
  __shared__ short Bh[2][64*40];
  __shared__ short Bl[2][64*40];
  const int fid = blockIdx.x;
  const int wl  = (fid & 7) * 40 + (fid >> 3);
  const int y = wl / 5, x = wl % 5;
  const int m0 = y * 64, c0 = x * 64;
  const int t = threadIdx.x;
  const int lane = t & 63, w = t >> 6;
  const int wr = w >> 1, wc = w & 1;
  // staging: thread t -> row t>>2 (0..63), kq (t&3)*8
  const int srow = t >> 2, kq = (t & 3) * 8;
  const bool bok = (c0 + srow) < 300;
  const float* Arow = A + (size_t)(m0 + srow) * 768 + kq;
  const float* Wrow = W + (size_t)(c0 + srow) * 768 + kq;
  float4 ra0, ra1, rb0, rb1;
#define K1_LD(kt) { \
    ra0 = *(const float4*)(Arow + (kt)); \
    ra1 = *(const float4*)(Arow + (kt) + 4); \
    rb0 = bok ? *(const float4*)(Wrow + (kt)) : f4z(); \
    rb1 = bok ? *(const float4*)(Wrow + (kt) + 4) : f4z(); }
  K1_LD(0)
  f32x4 acc[2][2];
  #pragma unroll
  for (int i = 0; i < 2; i++)
    #pragma unroll
    for (int j = 0; j < 2; j++)
      acc[i][j] = (f32x4){0.f, 0.f, 0.f, 0.f};
  // fragment read indices
  const int fr = lane & 15;
  const int fk = (lane >> 4) * 8;
  int p = 0;
  for (int tile = 0; tile < 24; ++tile){
    { // convert + write LDS[p]
      float av[8] = {ra0.x, ra0.y, ra0.z, ra0.w, ra1.x, ra1.y, ra1.z, ra1.w};
      float bv[8] = {rb0.x, rb0.y, rb0.z, rb0.w, rb1.x, rb1.y, rb1.z, rb1.w};
      short8 vah, val_, vbh, vbl;
      #pragma unroll
      for (int i = 0; i < 8; i++){
        unsigned short hh = f2bf(av[i]);
        vah[i] = (short)hh;
        val_[i] = (short)f2bf(av[i] - bf2f(hh));
        unsigned short gh = f2bf(bv[i]);
        vbh[i] = (short)gh;
        vbl[i] = (short)f2bf(bv[i] - bf2f(gh));
      }
      const int o = srow * 40 + kq;
      *(short8*)&Ah[p][o] = vah;
      *(short8*)&Al[p][o] = val_;
      *(short8*)&Bh[p][o] = vbh;
      *(short8*)&Bl[p][o] = vbl;
    }
    __syncthreads();
    if (tile < 23) K1_LD((tile + 1) * 32)
    { // MFMA phase on LDS[p]
      const int a0o = (wr*32      + fr) * 40 + fk;
      const int a1o = (wr*32 + 16 + fr) * 40 + fk;
      const int b0o = (wc*32      + fr) * 40 + fk;
      const int b1o = (wc*32 + 16 + fr) * 40 + fk;
      short8 fAh[2], fAl[2], fBh[2], fBl[2];
      fAh[0] = *(short8*)&Ah[p][a0o]; fAh[1] = *(short8*)&Ah[p][a1o];
      fAl[0] = *(short8*)&Al[p][a0o]; fAl[1] = *(short8*)&Al[p][a1o];
      fBh[0] = *(short8*)&Bh[p][b0o]; fBh[1] = *(short8*)&Bh[p][b1o];
      fBl[0] = *(short8*)&Bl[p][b0o]; fBl[1] = *(short8*)&Bl[p][b1o];
      #pragma unroll
      for (int sm = 0; sm < 2; sm++)
        #pragma unroll
        for (int sn = 0; sn < 2; sn++){
          acc[sm][sn] = __builtin_amdgcn_mfma_f32_16x16x32_bf16(fAh[sm], fBh[sn], acc[sm][sn], 0, 0, 0);
          acc[sm][sn] = __builtin_amdgcn_mfma_f32_16x16x32_bf16(fAh[sm], fBl[sn], acc[sm][sn], 0, 0, 0);
          acc[sm][sn] = __builtin_amdgcn_mfma_f32_16x16x32_bf16(fAl[sm], fBh[sn], acc[sm][sn], 0, 0, 0);
        }
    }
    p ^= 1;
  }
#undef K1_LD
  // epilogue: C/D layout col=lane&15, row=(lane>>4)*4+r (verified m89)
  const int crow = (lane >> 4) * 4;
  const int ccol = lane & 15;
  #pragma unroll
  for (int sn = 0; sn < 2; sn++){
    const int gcol = c0 + wc*32 + sn*16 + ccol;
    if (gcol < 300){
      const float bi = Wb[gcol];
      #pragma unroll
      for (int sm = 0; sm < 2; sm++){
        const int rbase = m0 + wr*32 + sm*16 + crow;
        #pragma unroll
        for (int r = 0; r < 4; r++)
          H[(size_t)(rbase + r) * 300 + gcol] = acc[sm][sn][r] + bi;
      }
    }
  }
}

// ================= K2: S = H @ Bmat^T (+a1b cols<64)  [4096 x 128], K=300 ==========
__global__ __launch_bounds__(256) void k2_s(const float* __restrict__ Hm,
                                            const float* __restrict__ a1w,
                                            const float* __restrict__ a1b,
                                            float* __restrict__ S){
  __shared__ float As[2][32*40];
  __shared__ float Bs[2][32*136];
  const int bid = blockIdx.x;
  const int y = (bid & 7) * 16 + (bid >> 3);
  const int m0 = y * 32;
  const int t = threadIdx.x;
  const int tr4 = (t >> 5) * 4, tc = t & 31;
  const int arow = t >> 3, akq = t & 7;
  const int bn = t & 127, bkh = t >> 7;
  const float* brp = (bn < 64) ? &a1w[(size_t)bn * 600] : &a1w[(size_t)(bn - 64) * 600 + 300];
  float4 ha, b4[4];
  float4 acc[4];
  #pragma unroll
  for (int i = 0; i < 4; i++) acc[i] = f4z();
#define K2_LD(kt) { \
    const int ka = (kt) + akq*4; \
    ha = (ka < 300) ? *(const float4*)&Hm[(size_t)(m0 + arow)*300 + ka] : f4z(); \
    _Pragma("unroll") \
    for (int j = 0; j < 4; j++){ \
      const int kb = (kt) + bkh*16 + 4*j; \
      b4[j] = (kb < 300) ? *(const float4*)&brp[kb] : f4z(); \
    } }
  K2_LD(0)
  int p = 0;
  for (int tile = 0; tile < 10; ++tile){
    #pragma unroll
    for (int jj = 0; jj < 4; jj++)
      As[p][(akq*4 + jj)*40 + ((((arow>>2) ^ akq) & 7) << 2) + (arow & 3)] = F4C(ha, jj);
    #pragma unroll
    for (int jj = 0; jj < 16; jj++){
      const int kl = bkh*16 + jj;
      const int swb = (kl >> 2) & 7;
      Bs[p][kl*136 + (((bn>>2) ^ swb) << 2) + (bn & 3)] = F4C(b4[jj>>2], jj&3);
    }
    __syncthreads();
    if (tile < 9) K2_LD((tile + 1) * 32)
    #pragma unroll
    for (int kk = 0; kk < 32; kk++){
      const int sw = (kk >> 2) & 7;
      const float4 av = *(const float4*)&As[p][kk*40 + (((t>>5) ^ sw) << 2)];
      const float4 bv = *(const float4*)&Bs[p][kk*136 + ((tc ^ sw) << 2)];
      acc[0].x += av.x*bv.x; acc[0].y += av.x*bv.y; acc[0].z += av.x*bv.z; acc[0].w += av.x*bv.w;
      acc[1].x += av.y*bv.x; acc[1].y += av.y*bv.y; acc[1].z += av.y*bv.z; acc[1].w += av.y*bv.w;
      acc[2].x += av.z*bv.x; acc[2].y += av.z*bv.y; acc[2].z += av.z*bv.z; acc[2].w += av.z*bv.w;
      acc[3].x += av.w*bv.x; acc[3].y += av.w*bv.y; acc[3].z += av.w*bv.z; acc[3].w += av.w*bv.w;
    }
    p ^= 1;
  }
#undef K2_LD
  const int tc4 = tc * 4;
  float4 bi = f4z();
  if (tc4 < 64) bi = *(const float4*)&a1b[tc4];
  #pragma unroll
  for (int i = 0; i < 4; i++){
    float4 o = make_float4(acc[i].x+bi.x, acc[i].y+bi.y, acc[i].z+bi.z, acc[i].w+bi.w);
    *(float4*)&S[(size_t)(m0 + tr4 + i) * 128 + tc4] = o;
  }
}

// ================= K3: logits + mask + per-block (max, sum-exp) =====================
__global__ __launch_bounds__(256) void k3_logits(const float* __restrict__ S,
                                                 const float* __restrict__ adj,
                                                 const float* __restrict__ a2w,
                                                 const float* __restrict__ a2b,
                                                 float* __restrict__ L,
                                                 float* __restrict__ bm,
                                                 float* __restrict__ bs){
  __shared__ float si_s[32*68];
  __shared__ float sj_s[64*68];
  __shared__ float w_s[64];
  __shared__ float redm[4];
  __shared__ float reds[4];
  __shared__ float smax;
  const int b  = blockIdx.z;
  const int i0 = blockIdx.y * 32;
  const int j0 = blockIdx.x * 64;
  const int t  = threadIdx.x;
  if (t < 16) *(float4*)&w_s[t*4] = *(const float4*)&a2w[t*4];
  #pragma unroll
  for (int q = 0; q < 2; q++){
    int c = t + q*256; int r = c >> 4, c4 = c & 15;
    *(float4*)&si_s[r*68 + c4*4] = *(const float4*)&S[(size_t)(b*512 + i0 + r)*128 + c4*4];
  }
  #pragma unroll
  for (int q = 0; q < 4; q++){
    int c = t + q*256; int r = c >> 4, c4 = c & 15;
    *(float4*)&sj_s[r*68 + c4*4] = *(const float4*)&S[(size_t)(b*512 + j0 + r)*128 + 64 + c4*4];
  }
  __syncthreads();
  const int j = t & 63, iq = t >> 6;
  const float a2bv = a2b[0];
  float4 acc[8];
  #pragma unroll
  for (int ii = 0; ii < 8; ii++) acc[ii] = f4z();
  #pragma unroll
  for (int k4 = 0; k4 < 16; k4++){
    const float4 sj4 = *(const float4*)&sj_s[j*68 + k4*4];
    const float4 w4  = *(const float4*)&w_s[k4*4];
    #pragma unroll
    for (int ii = 0; ii < 8; ii++){
      const int i = ii*4 + iq;
      const float4 si4 = *(const float4*)&si_s[i*68 + k4*4];
      acc[ii].x += fmaxf(si4.x + sj4.x, 0.f) * w4.x;
      acc[ii].y += fmaxf(si4.y + sj4.y, 0.f) * w4.y;
      acc[ii].z += fmaxf(si4.z + sj4.z, 0.f) * w4.z;
      acc[ii].w += fmaxf(si4.w + sj4.w, 0.f) * w4.w;
    }
  }
  float l_arr[8];
  float locmax = -3e38f;
  #pragma unroll
  for (int ii = 0; ii < 8; ii++){
    const int i = ii*4 + iq;
    float e = ((acc[ii].x + acc[ii].y) + (acc[ii].z + acc[ii].w)) + a2bv;
    e = (e >= 0.f) ? e : 0.01f * e;
    size_t idxg = (size_t)(b*512 + i0 + i)*512 + j0 + j;
    float l = (adj[idxg] != 0.f) ? e : NEGINF;
    l_arr[ii] = l;
    L[idxg] = l;
    locmax = fmaxf(locmax, l);
  }
  float m = waveRedMax(locmax);
  if ((t & 63) == 0) redm[t >> 6] = m;
  __syncthreads();
  if (t == 0) smax = fmaxf(fmaxf(redm[0], redm[1]), fmaxf(redm[2], redm[3]));
  __syncthreads();
  const float mb = smax;
  float sacc = 0.f;
  #pragma unroll
  for (int ii = 0; ii < 8; ii++) sacc += __expf(l_arr[ii] - mb);
  sacc = waveRedSum(sacc);
  if ((t & 63) == 0) reds[t >> 6] = sacc;
  __syncthreads();
  if (t == 0){
    const int bid = (blockIdx.z * 16 + blockIdx.y) * 8 + blockIdx.x;
    bm[bid] = mb;
    bs[bid] = (reds[0] + reds[1]) + (reds[2] + reds[3]);
  }
}

// ================= K6: combine per-block (m,s) -> per-batch (maxg, sums) ============
__global__ __launch_bounds__(128) void k6_red(const float* __restrict__ bm,
                                              const float* __restrict__ bs,
                                              float* __restrict__ sums,
                                              float* __restrict__ maxg){
  const int b = blockIdx.x, t = threadIdx.x;
  const float m = bm[b*128 + t];
  float mm = waveRedMax(m);
  __shared__ float r2m[2];
  __shared__ float mgs;
  if ((t & 63) == 0) r2m[t >> 6] = mm;
  __syncthreads();
  if (t == 0) mgs = fmaxf(r2m[0], r2m[1]);
  __syncthreads();
  const float mg = mgs;
  float v = bs[b*128 + t] * __expf(m - mg);
  v = waveRedSum(v);
  __shared__ float r2s[2];
  if ((t & 63) == 0) r2s[t >> 6] = v;
  __syncthreads();
  if (t == 0){ sums[b] = r2s[0] + r2s[1]; maxg[b] = mg; }
}

// ================= K7: out = (exp(L-maxg) @ H) / sums; per-batch [512x300] ==========
__global__ __launch_bounds__(512) void k7_out(const float* __restrict__ Lr,
                                              const float* __restrict__ Hm,
                                              const float* __restrict__ sums,
                                              const float* __restrict__ maxg,
                                              float* __restrict__ out){
  __shared__ float LSH[8][2304];
  float* CB = &LSH[0][0];
  const int fid = blockIdx.x;
  const int b  = fid & 7;
  const int idx = fid >> 3;
  const int y = idx / 5, x = idx % 5;
  const int m0 = y * 64, c0 = x * 64;
  const int t = threadIdx.x;
  const int w = t >> 6, lane = t & 63;
  const int g = lane >> 3, h = lane & 7;
  const int lr = lane >> 2, lk = lane & 3;
  const int kr = lane >> 2, cq = lane & 3;
  float* As = &LSH[w][0];
  float* Bs = &LSH[w][1152];
  const int kw = w * 64;
  const float mx = maxg[b];
  const float* Hb = Hm + (size_t)(b*512) * 300;
  float4 a4[4], b4[4], accL[8], accH[8];
  #pragma unroll
  for (int i = 0; i < 8; i++){ accL[i] = f4z(); accH[i] = f4z(); }
#define K7_LDA(kt) { _Pragma("unroll") \
  for (int q = 0; q < 4; q++){ \
    const int row = lr + 16*q; \
    a4[q] = *(const float4*)&Lr[(size_t)(b*512 + m0 + row)*512 + (kt) + lk*4]; } }
#define K7_LDB(kt) { \
    const float* hr = Hb + (size_t)((kt) + kr) * 300; \
    _Pragma("unroll") \
    for (int j = 0; j < 4; j++){ \
      const int colj = c0 + cq*16 + 4*j; \
      b4[j] = (colj < 300) ? *(const float4*)&hr[colj] : f4z(); } }
  K7_LDA(kw)
  K7_LDB(kw)
  for (int tile = 0; tile < 4; ++tile){
    #pragma unroll
    for (int q = 0; q < 4; q++){
      const int rpos = ((((lr >> 2) + 4*q) ^ lk) << 2) | (lr & 3);
      #pragma unroll
      for (int j = 0; j < 4; j++)
        As[(lk*4 + j)*72 + rpos] = __expf(F4C(a4[q], j) - mx);
    }
    {
      const int swb = (kr >> 2) & 3;
      #pragma unroll
      for (int j = 0; j < 4; j++)
        *(float4*)&Bs[kr*72 + (((cq*4 + j) ^ swb) << 2)] = b4[j];
    }
    if (tile < 3){
      const int ofs = kw + (tile + 1) * 16;
      K7_LDA(ofs)
      K7_LDB(ofs)
    }
    #pragma unroll
    for (int kk = 0; kk < 16; kk++){
      const int sw = (kk >> 2) & 3;
      const float4 aL = *(const float4*)&As[kk*72 + (((2*g    ) ^ sw) << 2)];
      const float4 aH = *(const float4*)&As[kk*72 + (((2*g + 1) ^ sw) << 2)];
      const float4 bL = *(const float4*)&Bs[kk*72 + (((2*h    ) ^ sw) << 2)];
      const float4 bH = *(const float4*)&Bs[kk*72 + (((2*h + 1) ^ sw) << 2)];
      const float am[8] = {aL.x,aL.y,aL.z,aL.w,aH.x,aH.y,aH.z,aH.w};
      #pragma unroll
      for (int i = 0; i < 8; i++){
        accL[i].x += am[i]*bL.x; accL[i].y += am[i]*bL.y;
        accL[i].z += am[i]*bL.z; accL[i].w += am[i]*bL.w;
        accH[i].x += am[i]*bH.x; accH[i].y += am[i]*bH.y;
        accH[i].z += am[i]*bH.z; accH[i].w += am[i]*bH.w;
      }
    }
  }
#undef K7_LDA
#undef K7_LDB
  __syncthreads();
  if (w >= 4){
    #pragma unroll
    for (int i = 0; i < 8; i++){
      const int r = g*8 + i;
      *(float4*)&CB[(w-4)*4352 + r*68 + h*8    ] = accL[i];
      *(float4*)&CB[(w-4)*4352 + r*68 + h*8 + 4] = accH[i];
    }
  }
  __syncthreads();
  if (w < 4){
    #pragma unroll
    for (int i = 0; i < 8; i++){
      const int r = g*8 + i;
      const float4 u = *(const float4*)&CB[w*4352 + r*68 + h*8];
      const float4 v = *(const float4*)&CB[w*4352 + r*68 + h*8 + 4];
      accL[i].x += u.x; accL[i].y += u.y; accL[i].z += u.z; accL[i].w += u.w;
      accH[i].x += v.x; accH[i].y += v.y; accH[i].z += v.z; accH[i].w += v.w;
    }
  }
  __syncthreads();
  if (w == 2 || w == 3){
    #pragma unroll
    for (int i = 0; i < 8; i++){
      const int r = g*8 + i;
      *(float4*)&CB[(w-2)*4352 + r*68 + h*8    ] = accL[i];
      *(float4*)&CB[(w-2)*4352 + r*68 + h*8 + 4] = accH[i];
    }
  }
  __syncthreads();
  if (w < 2){
    #pragma unroll
    for (int i = 0; i < 8; i++){
      const int r = g*8 + i;
      const float4 u = *(const float4*)&CB[w*4352 + r*68 + h*8];
      const float4 v = *(const float4*)&CB[w*4352 + r*68 + h*8 + 4];
      accL[i].x += u.x; accL[i].y += u.y; accL[i].z += u.z; accL[i].w += u.w;
      accH[i].x += v.x; accH[i].y += v.y; accH[i].z += v.z; accH[i].w += v.w;
      *(float4*)&CB[w*4352 + r*68 + h*8    ] = accL[i];
      *(float4*)&CB[w*4352 + r*68 + h*8 + 4] = accH[i];
    }
  }
  __syncthreads();
  const float invs = 1.0f / sums[b];
  const int fr = t >> 3, fc = (t & 7) * 8;
  const int gcol = c0 + fc;
  const float4* p0 = (const float4*)&CB[fr*68 + fc];
  const float4* p1 = (const float4*)&CB[4352 + fr*68 + fc];
  if (gcol < 300){
    const float4 u = p0[0], v = p1[0];
    *(float4*)&out[(size_t)(b*512 + m0 + fr)*300 + gcol] =
      make_float4((u.x+v.x)*invs, (u.y+v.y)*invs, (u.z+v.z)*invs, (u.w+v.w)*invs);
  }
  if (gcol + 4 < 300){
    const float4 u = p0[1], v = p1[1];
    *(float4*)&out[(size_t)(b*512 + m0 + fr)*300 + gcol + 4] =
      make_float4((u.x+v.x)*invs, (u.y+v.y)*invs, (u.z+v.z)*invs, (u.w+v.w)*invs);
  }
}

extern "C" void kernel_launch(void* const* d_in, const int* in_sizes, int n_in,
                              void* d_out, int out_size, void* d_ws, size_t ws_size,
                              hipStream_t stream){
  const float* adj  = (const float*)d_in[0];
  const float* feat = (const float*)d_in[1];
  const float* Ww   = (const float*)d_in[2];
  const float* Wb   = (const float*)d_in[3];
  const float* a1w  = (const float*)d_in[4];
  const float* a1b  = (const float*)d_in[5];
  const float* a2w  = (const float*)d_in[6];
  const float* a2b  = (const float*)d_in[7];
  float* out = (float*)d_out;
  char* ws = (char*)d_ws;

  float* H    = (float*)(ws + 0);           // 4,915,200 B
  float* S    = (float*)(ws + 4915200);     // 2,097,152 B
  float* L    = (float*)(ws + 7012352);     // 8,388,608 B
  float* bm   = (float*)(ws + 15400960);    // 4,096 B
  float* bs   = (float*)(ws + 15405056);    // 4,096 B
  float* sums = (float*)(ws + 15409152);    // 32 B
  float* maxg = (float*)(ws + 15409216);    // 32 B

  k1_h     <<<dim3(320),      dim3(256), 0, stream>>>(feat, Ww, Wb, H);
  k2_s     <<<dim3(128),      dim3(256), 0, stream>>>(H, a1w, a1b, S);
  k3_logits<<<dim3(8, 16, 8), dim3(256), 0, stream>>>(S, adj, a2w, a2b, L, bm, bs);
  k6_red   <<<dim3(8),        dim3(128), 0, stream>>>(bm, bs, sums, maxg);
  k7_out   <<<dim3(320),      dim3(512), 0, stream>>>(L, H, sums, maxg, out);
}

// Round 15
// 83.229 us; speedup vs baseline: 2.4173x; 1.4333x over previous
//
#include <hip/hip_runtime.h>
// R15: k3 -> readlane-si (si off the LDS pipe; 2 LDS reads/k4), VGPR diet.
//      k7 -> MFMA split-bf16 (k1's proven scheme) + transposed swizzled B staging.
//      k1 (MFMA, proven R14), k2, k6 unchanged.

#define NEGINF (-1e30f)

typedef __attribute__((ext_vector_type(8))) short short8;
typedef __attribute__((ext_vector_type(4))) float f32x4;

__device__ inline float waveRedSum(float v){
  #pragma unroll
  for (int o = 32; o > 0; o >>= 1) v += __shfl_down(v, o, 64);
  return v;
}
__device__ inline float waveRedMax(float v){
  #pragma unroll
  for (int o = 32; o > 0; o >>= 1) v = fmaxf(v, __shfl_down(v, o, 64));
  return v;
}
__device__ inline float4 f4z(){ return make_float4(0.f,0.f,0.f,0.f); }
#define F4C(v, c) ((c)==0?(v).x:(c)==1?(v).y:(c)==2?(v).z:(v).w)

__device__ inline unsigned short f2bf(float f){
  unsigned u = __float_as_uint(f);
  unsigned r = u + 0x7fffu + ((u >> 16) & 1u);
  return (unsigned short)(r >> 16);
}
__device__ inline float bf2f(unsigned short h){
  return __uint_as_float(((unsigned)h) << 16);
}

// ================= K1: H = feat @ W^T + Wb  [4096 x 300], K=768, MFMA ==============
__global__ __launch_bounds__(256) void k1_h(const float* __restrict__ A,
                                            const float* __restrict__ W,
                                            const float* __restrict__ Wb,
                                            float* __restrict__ H){
  __shared__ short Ah[2][64*40];
  __shared__ short Al[2][64*40];
  __shared__ short Bh[2][64*40];
  __shared__ short Bl[2][64*40];
  const int fid = blockIdx.x;
  const int wl  = (fid & 7) * 40 + (fid >> 3);
  const int y = wl / 5, x = wl % 5;
  const int m0 = y * 64, c0 = x * 64;
  const int t = threadIdx.x;
  const int lane = t & 63, w = t >> 6;
  const int wr = w >> 1, wc = w & 1;
  const int srow = t >> 2, kq = (t & 3) * 8;
  const bool bok = (c0 + srow) < 300;
  const float* Arow = A + (size_t)(m0 + srow) * 768 + kq;
  const float* Wrow = W + (size_t)(c0 + srow) * 768 + kq;
  float4 ra0, ra1, rb0, rb1;
#define K1_LD(kt) { \
    ra0 = *(const float4*)(Arow + (kt)); \
    ra1 = *(const float4*)(Arow + (kt) + 4); \
    rb0 = bok ? *(const float4*)(Wrow + (kt)) : f4z(); \
    rb1 = bok ? *(const float4*)(Wrow + (kt) + 4) : f4z(); }
  K1_LD(0)
  f32x4 acc[2][2];
  #pragma unroll
  for (int i = 0; i < 2; i++)
    #pragma unroll
    for (int j = 0; j < 2; j++)
      acc[i][j] = (f32x4){0.f, 0.f, 0.f, 0.f};
  const int fr = lane & 15;
  const int fk = (lane >> 4) * 8;
  int p = 0;
  for (int tile = 0; tile < 24; ++tile){
    {
      float av[8] = {ra0.x, ra0.y, ra0.z, ra0.w, ra1.x, ra1.y, ra1.z, ra1.w};
      float bv[8] = {rb0.x, rb0.y, rb0.z, rb0.w, rb1.x, rb1.y, rb1.z, rb1.w};
      short8 vah, val_, vbh, vbl;
      #pragma unroll
      for (int i = 0; i < 8; i++){
        unsigned short hh = f2bf(av[i]);
        vah[i] = (short)hh;
        val_[i] = (short)f2bf(av[i] - bf2f(hh));
        unsigned short gh = f2bf(bv[i]);
        vbh[i] = (short)gh;
        vbl[i] = (short)f2bf(bv[i] - bf2f(gh));
      }
      const int o = srow * 40 + kq;
      *(short8*)&Ah[p][o] = vah;
      *(short8*)&Al[p][o] = val_;
      *(short8*)&Bh[p][o] = vbh;
      *(short8*)&Bl[p][o] = vbl;
    }
    __syncthreads();
    if (tile < 23) K1_LD((tile + 1) * 32)
    {
      const int a0o = (wr*32      + fr) * 40 + fk;
      const int a1o = (wr*32 + 16 + fr) * 40 + fk;
      const int b0o = (wc*32      + fr) * 40 + fk;
      const int b1o = (wc*32 + 16 + fr) * 40 + fk;
      short8 fAh[2], fAl[2], fBh[2], fBl[2];
      fAh[0] = *(short8*)&Ah[p][a0o]; fAh[1] = *(short8*)&Ah[p][a1o];
      fAl[0] = *(short8*)&Al[p][a0o]; fAl[1] = *(short8*)&Al[p][a1o];
      fBh[0] = *(short8*)&Bh[p][b0o]; fBh[1] = *(short8*)&Bh[p][b1o];
      fBl[0] = *(short8*)&Bl[p][b0o]; fBl[1] = *(short8*)&Bl[p][b1o];
      #pragma unroll
      for (int sm = 0; sm < 2; sm++)
        #pragma unroll
        for (int sn = 0; sn < 2; sn++){
          acc[sm][sn] = __builtin_amdgcn_mfma_f32_16x16x32_bf16(fAh[sm], fBh[sn], acc[sm][sn], 0, 0, 0);
          acc[sm][sn] = __builtin_amdgcn_mfma_f32_16x16x32_bf16(fAh[sm], fBl[sn], acc[sm][sn], 0, 0, 0);
          acc[sm][sn] = __builtin_amdgcn_mfma_f32_16x16x32_bf16(fAl[sm], fBh[sn], acc[sm][sn], 0, 0, 0);
        }
    }
    p ^= 1;
  }
#undef K1_LD
  const int crow = (lane >> 4) * 4;
  const int ccol = lane & 15;
  #pragma unroll
  for (int sn = 0; sn < 2; sn++){
    const int gcol = c0 + wc*32 + sn*16 + ccol;
    if (gcol < 300){
      const float bi = Wb[gcol];
      #pragma unroll
      for (int sm = 0; sm < 2; sm++){
        const int rbase = m0 + wr*32 + sm*16 + crow;
        #pragma unroll
        for (int r = 0; r < 4; r++)
          H[(size_t)(rbase + r) * 300 + gcol] = acc[sm][sn][r] + bi;
      }
    }
  }
}

// ================= K2: S = H @ Bmat^T (+a1b cols<64)  [4096 x 128], K=300 ==========
__global__ __launch_bounds__(256) void k2_s(const float* __restrict__ Hm,
                                            const float* __restrict__ a1w,
                                            const float* __restrict__ a1b,
                                            float* __restrict__ S){
  __shared__ float As[2][32*40];
  __shared__ float Bs[2][32*136];
  const int bid = blockIdx.x;
  const int y = (bid & 7) * 16 + (bid >> 3);
  const int m0 = y * 32;
  const int t = threadIdx.x;
  const int tr4 = (t >> 5) * 4, tc = t & 31;
  const int arow = t >> 3, akq = t & 7;
  const int bn = t & 127, bkh = t >> 7;
  const float* brp = (bn < 64) ? &a1w[(size_t)bn * 600] : &a1w[(size_t)(bn - 64) * 600 + 300];
  float4 ha, b4[4];
  float4 acc[4];
  #pragma unroll
  for (int i = 0; i < 4; i++) acc[i] = f4z();
#define K2_LD(kt) { \
    const int ka = (kt) + akq*4; \
    ha = (ka < 300) ? *(const float4*)&Hm[(size_t)(m0 + arow)*300 + ka] : f4z(); \
    _Pragma("unroll") \
    for (int j = 0; j < 4; j++){ \
      const int kb = (kt) + bkh*16 + 4*j; \
      b4[j] = (kb < 300) ? *(const float4*)&brp[kb] : f4z(); \
    } }
  K2_LD(0)
  int p = 0;
  for (int tile = 0; tile < 10; ++tile){
    #pragma unroll
    for (int jj = 0; jj < 4; jj++)
      As[p][(akq*4 + jj)*40 + ((((arow>>2) ^ akq) & 7) << 2) + (arow & 3)] = F4C(ha, jj);
    #pragma unroll
    for (int jj = 0; jj < 16; jj++){
      const int kl = bkh*16 + jj;
      const int swb = (kl >> 2) & 7;
      Bs[p][kl*136 + (((bn>>2) ^ swb) << 2) + (bn & 3)] = F4C(b4[jj>>2], jj&3);
    }
    __syncthreads();
    if (tile < 9) K2_LD((tile + 1) * 32)
    #pragma unroll
    for (int kk = 0; kk < 32; kk++){
      const int sw = (kk >> 2) & 7;
      const float4 av = *(const float4*)&As[p][kk*40 + (((t>>5) ^ sw) << 2)];
      const float4 bv = *(const float4*)&Bs[p][kk*136 + ((tc ^ sw) << 2)];
      acc[0].x += av.x*bv.x; acc[0].y += av.x*bv.y; acc[0].z += av.x*bv.z; acc[0].w += av.x*bv.w;
      acc[1].x += av.y*bv.x; acc[1].y += av.y*bv.y; acc[1].z += av.y*bv.z; acc[1].w += av.y*bv.w;
      acc[2].x += av.z*bv.x; acc[2].y += av.z*bv.y; acc[2].z += av.z*bv.z; acc[2].w += av.z*bv.w;
      acc[3].x += av.w*bv.x; acc[3].y += av.w*bv.y; acc[3].z += av.w*bv.z; acc[3].w += av.w*bv.w;
    }
    p ^= 1;
  }
#undef K2_LD
  const int tc4 = tc * 4;
  float4 bi = f4z();
  if (tc4 < 64) bi = *(const float4*)&a1b[tc4];
  #pragma unroll
  for (int i = 0; i < 4; i++){
    float4 o = make_float4(acc[i].x+bi.x, acc[i].y+bi.y, acc[i].z+bi.z, acc[i].w+bi.w);
    *(float4*)&S[(size_t)(m0 + tr4 + i) * 128 + tc4] = o;
  }
}

// ================= K3: logits + mask + per-block (max, sum-exp) =====================
// si via per-lane VGPR distribution + readlane (no si LDS); sj/w in LDS.
__global__ __launch_bounds__(256) void k3_logits(const float* __restrict__ S,
                                                 const float* __restrict__ adj,
                                                 const float* __restrict__ a2w,
                                                 const float* __restrict__ a2b,
                                                 float* __restrict__ L,
                                                 float* __restrict__ bm,
                                                 float* __restrict__ bs){
  __shared__ float sj_s[64*68];
  __shared__ float w_s[64];
  __shared__ float redm[4];
  __shared__ float reds[4];
  __shared__ float smax;
  const int b  = blockIdx.z;
  const int i0 = blockIdx.y * 32;
  const int j0 = blockIdx.x * 64;
  const int t  = threadIdx.x;
  const int j = t & 63, iq = t >> 6;
  if (t < 16) *(float4*)&w_s[t*4] = *(const float4*)&a2w[t*4];
  #pragma unroll
  for (int q = 0; q < 4; q++){
    int c = t + q*256; int r = c >> 4, c4 = c & 15;
    *(float4*)&sj_s[r*68 + c4*4] = *(const float4*)&S[(size_t)(b*512 + j0 + r)*128 + 64 + c4*4];
  }
  // distributed si: lane k holds si[(r*4+iq)][k]; coalesced 256B loads
  float vsi[8];
  #pragma unroll
  for (int r = 0; r < 8; r++)
    vsi[r] = S[(size_t)(b*512 + i0 + r*4 + iq) * 128 + j];
  __syncthreads();
  const float a2bv = a2b[0];
  float accA[8][4];
  #pragma unroll
  for (int r = 0; r < 8; r++)
    #pragma unroll
    for (int c = 0; c < 4; c++) accA[r][c] = 0.f;
  #pragma unroll
  for (int k4 = 0; k4 < 16; k4++){
    const float4 sj4 = *(const float4*)&sj_s[j*68 + k4*4];
    const float4 w4  = *(const float4*)&w_s[k4*4];
    #pragma unroll
    for (int c = 0; c < 4; c++){
      const int k = k4*4 + c;
      const float sjc = F4C(sj4, c);
      const float wc  = F4C(w4, c);
      #pragma unroll
      for (int r = 0; r < 8; r++){
        const float s = __int_as_float(__builtin_amdgcn_readlane(__float_as_int(vsi[r]), k));
        accA[r][c] += fmaxf(s + sjc, 0.f) * wc;
      }
    }
  }
  float l_arr[8];
  float locmax = -3e38f;
  #pragma unroll
  for (int r = 0; r < 8; r++){
    const int i = r*4 + iq;
    float e = ((accA[r][0] + accA[r][1]) + (accA[r][2] + accA[r][3])) + a2bv;
    e = (e >= 0.f) ? e : 0.01f * e;
    size_t idxg = (size_t)(b*512 + i0 + i)*512 + j0 + j;
    float l = (adj[idxg] != 0.f) ? e : NEGINF;
    l_arr[r] = l;
    L[idxg] = l;
    locmax = fmaxf(locmax, l);
  }
  float m = waveRedMax(locmax);
  if ((t & 63) == 0) redm[t >> 6] = m;
  __syncthreads();
  if (t == 0) smax = fmaxf(fmaxf(redm[0], redm[1]), fmaxf(redm[2], redm[3]));
  __syncthreads();
  const float mb = smax;
  float sacc = 0.f;
  #pragma unroll
  for (int r = 0; r < 8; r++) sacc += __expf(l_arr[r] - mb);
  sacc = waveRedSum(sacc);
  if ((t & 63) == 0) reds[t >> 6] = sacc;
  __syncthreads();
  if (t == 0){
    const int bid = (blockIdx.z * 16 + blockIdx.y) * 8 + blockIdx.x;
    bm[bid] = mb;
    bs[bid] = (reds[0] + reds[1]) + (reds[2] + reds[3]);
  }
}

// ================= K6: combine per-block (m,s) -> per-batch (maxg, sums) ============
__global__ __launch_bounds__(128) void k6_red(const float* __restrict__ bm,
                                              const float* __restrict__ bs,
                                              float* __restrict__ sums,
                                              float* __restrict__ maxg){
  const int b = blockIdx.x, t = threadIdx.x;
  const float m = bm[b*128 + t];
  float mm = waveRedMax(m);
  __shared__ float r2m[2];
  __shared__ float mgs;
  if ((t & 63) == 0) r2m[t >> 6] = mm;
  __syncthreads();
  if (t == 0) mgs = fmaxf(r2m[0], r2m[1]);
  __syncthreads();
  const float mg = mgs;
  float v = bs[b*128 + t] * __expf(m - mg);
  v = waveRedSum(v);
  __shared__ float r2s[2];
  if ((t & 63) == 0) r2s[t >> 6] = v;
  __syncthreads();
  if (t == 0){ sums[b] = r2s[0] + r2s[1]; maxg[b] = mg; }
}

// ================= K7: out = (exp(L-maxg) @ H) / sums, MFMA split-bf16 ==============
// per-batch [512x300], K=512; B = H[k][n] transposed in staging (packed b32 writes,
// block-XOR swizzle kblk ^= n&3 on both write and frag-read sides).
__global__ __launch_bounds__(256) void k7_out(const float* __restrict__ Lr,
                                              const float* __restrict__ Hm,
                                              const float* __restrict__ sums,
                                              const float* __restrict__ maxg,
                                              float* __restrict__ out){
  __shared__ short Ah[2][64*40];
  __shared__ short Al[2][64*40];
  __shared__ short Bh[2][64*40];
  __shared__ short Bl[2][64*40];
  const int fid = blockIdx.x;
  const int b = fid & 7, idx = fid >> 3;
  const int y = idx / 5, x = idx % 5;
  const int m0 = y * 64, c0 = x * 64;
  const int t = threadIdx.x;
  const int lane = t & 63, wv = t >> 6;
  const int wr = wv >> 1, wc = wv & 1;
  const float mx = maxg[b];
  // A staging: row srow (L row m0+srow), k-chunk kq
  const int srow = t >> 2, kq = (t & 3) * 8;
  const float* Lrow = Lr + (size_t)(b*512 + m0 + srow) * 512 + kq;
  // B staging: tk -> k-pair, tn -> n-quad
  const int tk = t >> 4, tn = t & 15;
  const int k0 = tk * 2, n0 = tn * 4;
  const int gcolB = c0 + n0;
  const bool bok = gcolB < 300;           // gcolB multiple of 4, <=296 -> float4 safe
  float4 ra0, ra1, hb0, hb1;
#define K7_LD(kt) { \
    ra0 = *(const float4*)(Lrow + (kt)); \
    ra1 = *(const float4*)(Lrow + (kt) + 4); \
    const float* hr = Hm + (size_t)(b*512 + (kt) + k0) * 300 + gcolB; \
    hb0 = bok ? *(const float4*)hr : f4z(); \
    hb1 = bok ? *(const float4*)(hr + 300) : f4z(); }
  K7_LD(0)
  f32x4 acc[2][2];
  #pragma unroll
  for (int i = 0; i < 2; i++)
    #pragma unroll
    for (int jj = 0; jj < 2; jj++)
      acc[i][jj] = (f32x4){0.f, 0.f, 0.f, 0.f};
  const int fr = lane & 15;
  const int fg = lane >> 4;               // k-group 0..3
  const int fk = fg * 8;
  int p = 0;
  for (int tile = 0; tile < 16; ++tile){
    { // A: exp + split, linear [srow][40]
      float av[8] = {ra0.x, ra0.y, ra0.z, ra0.w, ra1.x, ra1.y, ra1.z, ra1.w};
      short8 vah, val_;
      #pragma unroll
      for (int i = 0; i < 8; i++){
        const float e = __expf(av[i] - mx);
        unsigned short hh = f2bf(e);
        vah[i] = (short)hh;
        val_[i] = (short)f2bf(e - bf2f(hh));
      }
      const int o = srow * 40 + kq;
      *(short8*)&Ah[p][o] = vah;
      *(short8*)&Al[p][o] = val_;
      // B: transpose 2k x 4n, packed b32 (k,k+1), swizzled block
      #pragma unroll
      for (int i = 0; i < 4; i++){
        const float v0 = F4C(hb0, i), v1 = F4C(hb1, i);
        const unsigned short h0 = f2bf(v0), h1 = f2bf(v1);
        const unsigned short l0 = f2bf(v0 - bf2f(h0)), l1 = f2bf(v1 - bf2f(h1));
        const int n = n0 + i;
        const int kbs = (k0 >> 3) ^ (n & 3);
        const int soff = n*40 + kbs*8 + (k0 & 7);
        *(unsigned*)&Bh[p][soff] = (unsigned)h0 | ((unsigned)h1 << 16);
        *(unsigned*)&Bl[p][soff] = (unsigned)l0 | ((unsigned)l1 << 16);
      }
    }
    __syncthreads();
    if (tile < 15) K7_LD((tile + 1) * 32)
    {
      const int a0o = (wr*32      + fr) * 40 + fk;
      const int a1o = (wr*32 + 16 + fr) * 40 + fk;
      const int nb0 = wc*32      + fr;
      const int nb1 = wc*32 + 16 + fr;
      const int b0o = nb0*40 + (fg ^ (nb0 & 3)) * 8;
      const int b1o = nb1*40 + (fg ^ (nb1 & 3)) * 8;
      short8 fAh[2], fAl[2], fBh[2], fBl[2];
      fAh[0] = *(short8*)&Ah[p][a0o]; fAh[1] = *(short8*)&Ah[p][a1o];
      fAl[0] = *(short8*)&Al[p][a0o]; fAl[1] = *(short8*)&Al[p][a1o];
      fBh[0] = *(short8*)&Bh[p][b0o]; fBh[1] = *(short8*)&Bh[p][b1o];
      fBl[0] = *(short8*)&Bl[p][b0o]; fBl[1] = *(short8*)&Bl[p][b1o];
      #pragma unroll
      for (int sm = 0; sm < 2; sm++)
        #pragma unroll
        for (int sn = 0; sn < 2; sn++){
          acc[sm][sn] = __builtin_amdgcn_mfma_f32_16x16x32_bf16(fAh[sm], fBh[sn], acc[sm][sn], 0, 0, 0);
          acc[sm][sn] = __builtin_amdgcn_mfma_f32_16x16x32_bf16(fAh[sm], fBl[sn], acc[sm][sn], 0, 0, 0);
          acc[sm][sn] = __builtin_amdgcn_mfma_f32_16x16x32_bf16(fAl[sm], fBh[sn], acc[sm][sn], 0, 0, 0);
        }
    }
    p ^= 1;
  }
#undef K7_LD
  const float invs = 1.0f / sums[b];
  const int crow = (lane >> 4) * 4;
  const int ccol = lane & 15;
  #pragma unroll
  for (int sn = 0; sn < 2; sn++){
    const int gcol = c0 + wc*32 + sn*16 + ccol;
    if (gcol < 300){
      #pragma unroll
      for (int sm = 0; sm < 2; sm++){
        const int rbase = m0 + wr*32 + sm*16 + crow;
        #pragma unroll
        for (int r = 0; r < 4; r++)
          out[(size_t)(b*512 + rbase + r) * 300 + gcol] = acc[sm][sn][r] * invs;
      }
    }
  }
}

extern "C" void kernel_launch(void* const* d_in, const int* in_sizes, int n_in,
                              void* d_out, int out_size, void* d_ws, size_t ws_size,
                              hipStream_t stream){
  const float* adj  = (const float*)d_in[0];
  const float* feat = (const float*)d_in[1];
  const float* Ww   = (const float*)d_in[2];
  const float* Wb   = (const float*)d_in[3];
  const float* a1w  = (const float*)d_in[4];
  const float* a1b  = (const float*)d_in[5];
  const float* a2w  = (const float*)d_in[6];
  const float* a2b  = (const float*)d_in[7];
  float* out = (float*)d_out;
  char* ws = (char*)d_ws;

  float* H    = (float*)(ws + 0);           // 4,915,200 B
  float* S    = (float*)(ws + 4915200);     // 2,097,152 B
  float* L    = (float*)(ws + 7012352);     // 8,388,608 B
  float* bm   = (float*)(ws + 15400960);    // 4,096 B
  float* bs   = (float*)(ws + 15405056);    // 4,096 B
  float* sums = (float*)(ws + 15409152);    // 32 B
  float* maxg = (float*)(ws + 15409216);    // 32 B

  k1_h     <<<dim3(320),      dim3(256), 0, stream>>>(feat, Ww, Wb, H);
  k2_s     <<<dim3(128),      dim3(256), 0, stream>>>(H, a1w, a1b, S);
  k3_logits<<<dim3(8, 16, 8), dim3(256), 0, stream>>>(S, adj, a2w, a2b, L, bm, bs);
  k6_red   <<<dim3(8),        dim3(128), 0, stream>>>(bm, bs, sums, maxg);
  k7_out   <<<dim3(320),      dim3(256), 0, stream>>>(L, H, sums, maxg, out);
}

// Round 16
// 77.127 us; speedup vs baseline: 2.6085x; 1.0791x over previous
//
#include <hip/hip_runtime.h>
// R16: k2 -> MFMA split-bf16 (k1's proven template; B rows k-contiguous, K=300
// padded to 320 with float4 guards). k1/k3/k6/k7 byte-identical to R15.

#define NEGINF (-1e30f)

typedef __attribute__((ext_vector_type(8))) short short8;
typedef __attribute__((ext_vector_type(4))) float f32x4;

__device__ inline float waveRedSum(float v){
  #pragma unroll
  for (int o = 32; o > 0; o >>= 1) v += __shfl_down(v, o, 64);
  return v;
}
__device__ inline float waveRedMax(float v){
  #pragma unroll
  for (int o = 32; o > 0; o >>= 1) v = fmaxf(v, __shfl_down(v, o, 64));
  return v;
}
__device__ inline float4 f4z(){ return make_float4(0.f,0.f,0.f,0.f); }
#define F4C(v, c) ((c)==0?(v).x:(c)==1?(v).y:(c)==2?(v).z:(v).w)

__device__ inline unsigned short f2bf(float f){
  unsigned u = __float_as_uint(f);
  unsigned r = u + 0x7fffu + ((u >> 16) & 1u);
  return (unsigned short)(r >> 16);
}
__device__ inline float bf2f(unsigned short h){
  return __uint_as_float(((unsigned)h) << 16);
}

// ================= K1: H = feat @ W^T + Wb  [4096 x 300], K=768, MFMA ==============
__global__ __launch_bounds__(256) void k1_h(const float* __restrict__ A,
                                            const float* __restrict__ W,
                                            const float* __restrict__ Wb,
                                            float* __restrict__ H){
  __shared__ short Ah[2][64*40];
  __shared__ short Al[2][64*40];
  __shared__ short Bh[2][64*40];
  __shared__ short Bl[2][64*40];
  const int fid = blockIdx.x;
  const int wl  = (fid & 7) * 40 + (fid >> 3);
  const int y = wl / 5, x = wl % 5;
  const int m0 = y * 64, c0 = x * 64;
  const int t = threadIdx.x;
  const int lane = t & 63, w = t >> 6;
  const int wr = w >> 1, wc = w & 1;
  const int srow = t >> 2, kq = (t & 3) * 8;
  const bool bok = (c0 + srow) < 300;
  const float* Arow = A + (size_t)(m0 + srow) * 768 + kq;
  const float* Wrow = W + (size_t)(c0 + srow) * 768 + kq;
  float4 ra0, ra1, rb0, rb1;
#define K1_LD(kt) { \
    ra0 = *(const float4*)(Arow + (kt)); \
    ra1 = *(const float4*)(Arow + (kt) + 4); \
    rb0 = bok ? *(const float4*)(Wrow + (kt)) : f4z(); \
    rb1 = bok ? *(const float4*)(Wrow + (kt) + 4) : f4z(); }
  K1_LD(0)
  f32x4 acc[2][2];
  #pragma unroll
  for (int i = 0; i < 2; i++)
    #pragma unroll
    for (int j = 0; j < 2; j++)
      acc[i][j] = (f32x4){0.f, 0.f, 0.f, 0.f};
  const int fr = lane & 15;
  const int fk = (lane >> 4) * 8;
  int p = 0;
  for (int tile = 0; tile < 24; ++tile){
    {
      float av[8] = {ra0.x, ra0.y, ra0.z, ra0.w, ra1.x, ra1.y, ra1.z, ra1.w};
      float bv[8] = {rb0.x, rb0.y, rb0.z, rb0.w, rb1.x, rb1.y, rb1.z, rb1.w};
      short8 vah, val_, vbh, vbl;
      #pragma unroll
      for (int i = 0; i < 8; i++){
        unsigned short hh = f2bf(av[i]);
        vah[i] = (short)hh;
        val_[i] = (short)f2bf(av[i] - bf2f(hh));
        unsigned short gh = f2bf(bv[i]);
        vbh[i] = (short)gh;
        vbl[i] = (short)f2bf(bv[i] - bf2f(gh));
      }
      const int o = srow * 40 + kq;
      *(short8*)&Ah[p][o] = vah;
      *(short8*)&Al[p][o] = val_;
      *(short8*)&Bh[p][o] = vbh;
      *(short8*)&Bl[p][o] = vbl;
    }
    __syncthreads();
    if (tile < 23) K1_LD((tile + 1) * 32)
    {
      const int a0o = (wr*32      + fr) * 40 + fk;
      const int a1o = (wr*32 + 16 + fr) * 40 + fk;
      const int b0o = (wc*32      + fr) * 40 + fk;
      const int b1o = (wc*32 + 16 + fr) * 40 + fk;
      short8 fAh[2], fAl[2], fBh[2], fBl[2];
      fAh[0] = *(short8*)&Ah[p][a0o]; fAh[1] = *(short8*)&Ah[p][a1o];
      fAl[0] = *(short8*)&Al[p][a0o]; fAl[1] = *(short8*)&Al[p][a1o];
      fBh[0] = *(short8*)&Bh[p][b0o]; fBh[1] = *(short8*)&Bh[p][b1o];
      fBl[0] = *(short8*)&Bl[p][b0o]; fBl[1] = *(short8*)&Bl[p][b1o];
      #pragma unroll
      for (int sm = 0; sm < 2; sm++)
        #pragma unroll
        for (int sn = 0; sn < 2; sn++){
          acc[sm][sn] = __builtin_amdgcn_mfma_f32_16x16x32_bf16(fAh[sm], fBh[sn], acc[sm][sn], 0, 0, 0);
          acc[sm][sn] = __builtin_amdgcn_mfma_f32_16x16x32_bf16(fAh[sm], fBl[sn], acc[sm][sn], 0, 0, 0);
          acc[sm][sn] = __builtin_amdgcn_mfma_f32_16x16x32_bf16(fAl[sm], fBh[sn], acc[sm][sn], 0, 0, 0);
        }
    }
    p ^= 1;
  }
#undef K1_LD
  const int crow = (lane >> 4) * 4;
  const int ccol = lane & 15;
  #pragma unroll
  for (int sn = 0; sn < 2; sn++){
    const int gcol = c0 + wc*32 + sn*16 + ccol;
    if (gcol < 300){
      const float bi = Wb[gcol];
      #pragma unroll
      for (int sm = 0; sm < 2; sm++){
        const int rbase = m0 + wr*32 + sm*16 + crow;
        #pragma unroll
        for (int r = 0; r < 4; r++)
          H[(size_t)(rbase + r) * 300 + gcol] = acc[sm][sn][r] + bi;
      }
    }
  }
}

// ================= K2: S = H @ Bmat^T (+a1b cols<64)  [4096 x 128], K=300, MFMA ====
// 64x64 tile, grid 128 (2 x-tiles x 64 y-tiles, XCD swizzle). K padded to 320.
__global__ __launch_bounds__(256) void k2_s(const float* __restrict__ Hm,
                                            const float* __restrict__ a1w,
                                            const float* __restrict__ a1b,
                                            float* __restrict__ S){
  __shared__ short Ah[2][64*40];
  __shared__ short Al[2][64*40];
  __shared__ short Bh[2][64*40];
  __shared__ short Bl[2][64*40];
  const int fid = blockIdx.x;
  const int wl  = (fid & 7) * 16 + (fid >> 3);   // 0..127
  const int y = wl >> 1, x = wl & 1;
  const int m0 = y * 64, c0 = x * 64;
  const int t = threadIdx.x;
  const int lane = t & 63, w = t >> 6;
  const int wr = w >> 1, wc = w & 1;
  const int srow = t >> 2, kq = (t & 3) * 8;
  const int brow = c0 + srow;                     // < 128, always valid
  const float* Arow = Hm + (size_t)(m0 + srow) * 300;
  const float* Brow = (brow < 64) ? (a1w + (size_t)brow * 600)
                                  : (a1w + (size_t)(brow - 64) * 600 + 300);
  float4 ra0, ra1, rb0, rb1;
#define K2_LD(kt) { \
    const int k = (kt) + kq; \
    ra0 = (k <= 296) ? *(const float4*)(Arow + k)     : f4z(); \
    ra1 = (k <= 292) ? *(const float4*)(Arow + k + 4) : f4z(); \
    rb0 = (k <= 296) ? *(const float4*)(Brow + k)     : f4z(); \
    rb1 = (k <= 292) ? *(const float4*)(Brow + k + 4) : f4z(); }
  K2_LD(0)
  f32x4 acc[2][2];
  #pragma unroll
  for (int i = 0; i < 2; i++)
    #pragma unroll
    for (int j = 0; j < 2; j++)
      acc[i][j] = (f32x4){0.f, 0.f, 0.f, 0.f};
  const int fr = lane & 15;
  const int fk = (lane >> 4) * 8;
  int p = 0;
  for (int tile = 0; tile < 10; ++tile){
    {
      float av[8] = {ra0.x, ra0.y, ra0.z, ra0.w, ra1.x, ra1.y, ra1.z, ra1.w};
      float bv[8] = {rb0.x, rb0.y, rb0.z, rb0.w, rb1.x, rb1.y, rb1.z, rb1.w};
      short8 vah, val_, vbh, vbl;
      #pragma unroll
      for (int i = 0; i < 8; i++){
        unsigned short hh = f2bf(av[i]);
        vah[i] = (short)hh;
        val_[i] = (short)f2bf(av[i] - bf2f(hh));
        unsigned short gh = f2bf(bv[i]);
        vbh[i] = (short)gh;
        vbl[i] = (short)f2bf(bv[i] - bf2f(gh));
      }
      const int o = srow * 40 + kq;
      *(short8*)&Ah[p][o] = vah;
      *(short8*)&Al[p][o] = val_;
      *(short8*)&Bh[p][o] = vbh;
      *(short8*)&Bl[p][o] = vbl;
    }
    __syncthreads();
    if (tile < 9) K2_LD((tile + 1) * 32)
    {
      const int a0o = (wr*32      + fr) * 40 + fk;
      const int a1o = (wr*32 + 16 + fr) * 40 + fk;
      const int b0o = (wc*32      + fr) * 40 + fk;
      const int b1o = (wc*32 + 16 + fr) * 40 + fk;
      short8 fAh[2], fAl[2], fBh[2], fBl[2];
      fAh[0] = *(short8*)&Ah[p][a0o]; fAh[1] = *(short8*)&Ah[p][a1o];
      fAl[0] = *(short8*)&Al[p][a0o]; fAl[1] = *(short8*)&Al[p][a1o];
      fBh[0] = *(short8*)&Bh[p][b0o]; fBh[1] = *(short8*)&Bh[p][b1o];
      fBl[0] = *(short8*)&Bl[p][b0o]; fBl[1] = *(short8*)&Bl[p][b1o];
      #pragma unroll
      for (int sm = 0; sm < 2; sm++)
        #pragma unroll
        for (int sn = 0; sn < 2; sn++){
          acc[sm][sn] = __builtin_amdgcn_mfma_f32_16x16x32_bf16(fAh[sm], fBh[sn], acc[sm][sn], 0, 0, 0);
          acc[sm][sn] = __builtin_amdgcn_mfma_f32_16x16x32_bf16(fAh[sm], fBl[sn], acc[sm][sn], 0, 0, 0);
          acc[sm][sn] = __builtin_amdgcn_mfma_f32_16x16x32_bf16(fAl[sm], fBh[sn], acc[sm][sn], 0, 0, 0);
        }
    }
    p ^= 1;
  }
#undef K2_LD
  const int crow = (lane >> 4) * 4;
  const int ccol = lane & 15;
  #pragma unroll
  for (int sn = 0; sn < 2; sn++){
    const int gcol = c0 + wc*32 + sn*16 + ccol;   // < 128, always valid
    const float bi = (gcol < 64) ? a1b[gcol] : 0.f;
    #pragma unroll
    for (int sm = 0; sm < 2; sm++){
      const int rbase = m0 + wr*32 + sm*16 + crow;
      #pragma unroll
      for (int r = 0; r < 4; r++)
        S[(size_t)(rbase + r) * 128 + gcol] = acc[sm][sn][r] + bi;
    }
  }
}

// ================= K3: logits + mask + per-block (max, sum-exp) =====================
// si via per-lane VGPR distribution + readlane (no si LDS); sj/w in LDS.
__global__ __launch_bounds__(256) void k3_logits(const float* __restrict__ S,
                                                 const float* __restrict__ adj,
                                                 const float* __restrict__ a2w,
                                                 const float* __restrict__ a2b,
                                                 float* __restrict__ L,
                                                 float* __restrict__ bm,
                                                 float* __restrict__ bs){
  __shared__ float sj_s[64*68];
  __shared__ float w_s[64];
  __shared__ float redm[4];
  __shared__ float reds[4];
  __shared__ float smax;
  const int b  = blockIdx.z;
  const int i0 = blockIdx.y * 32;
  const int j0 = blockIdx.x * 64;
  const int t  = threadIdx.x;
  const int j = t & 63, iq = t >> 6;
  if (t < 16) *(float4*)&w_s[t*4] = *(const float4*)&a2w[t*4];
  #pragma unroll
  for (int q = 0; q < 4; q++){
    int c = t + q*256; int r = c >> 4, c4 = c & 15;
    *(float4*)&sj_s[r*68 + c4*4] = *(const float4*)&S[(size_t)(b*512 + j0 + r)*128 + 64 + c4*4];
  }
  float vsi[8];
  #pragma unroll
  for (int r = 0; r < 8; r++)
    vsi[r] = S[(size_t)(b*512 + i0 + r*4 + iq) * 128 + j];
  __syncthreads();
  const float a2bv = a2b[0];
  float accA[8][4];
  #pragma unroll
  for (int r = 0; r < 8; r++)
    #pragma unroll
    for (int c = 0; c < 4; c++) accA[r][c] = 0.f;
  #pragma unroll
  for (int k4 = 0; k4 < 16; k4++){
    const float4 sj4 = *(const float4*)&sj_s[j*68 + k4*4];
    const float4 w4  = *(const float4*)&w_s[k4*4];
    #pragma unroll
    for (int c = 0; c < 4; c++){
      const int k = k4*4 + c;
      const float sjc = F4C(sj4, c);
      const float wc  = F4C(w4, c);
      #pragma unroll
      for (int r = 0; r < 8; r++){
        const float s = __int_as_float(__builtin_amdgcn_readlane(__float_as_int(vsi[r]), k));
        accA[r][c] += fmaxf(s + sjc, 0.f) * wc;
      }
    }
  }
  float l_arr[8];
  float locmax = -3e38f;
  #pragma unroll
  for (int r = 0; r < 8; r++){
    const int i = r*4 + iq;
    float e = ((accA[r][0] + accA[r][1]) + (accA[r][2] + accA[r][3])) + a2bv;
    e = (e >= 0.f) ? e : 0.01f * e;
    size_t idxg = (size_t)(b*512 + i0 + i)*512 + j0 + j;
    float l = (adj[idxg] != 0.f) ? e : NEGINF;
    l_arr[r] = l;
    L[idxg] = l;
    locmax = fmaxf(locmax, l);
  }
  float m = waveRedMax(locmax);
  if ((t & 63) == 0) redm[t >> 6] = m;
  __syncthreads();
  if (t == 0) smax = fmaxf(fmaxf(redm[0], redm[1]), fmaxf(redm[2], redm[3]));
  __syncthreads();
  const float mb = smax;
  float sacc = 0.f;
  #pragma unroll
  for (int r = 0; r < 8; r++) sacc += __expf(l_arr[r] - mb);
  sacc = waveRedSum(sacc);
  if ((t & 63) == 0) reds[t >> 6] = sacc;
  __syncthreads();
  if (t == 0){
    const int bid = (blockIdx.z * 16 + blockIdx.y) * 8 + blockIdx.x;
    bm[bid] = mb;
    bs[bid] = (reds[0] + reds[1]) + (reds[2] + reds[3]);
  }
}

// ================= K6: combine per-block (m,s) -> per-batch (maxg, sums) ============
__global__ __launch_bounds__(128) void k6_red(const float* __restrict__ bm,
                                              const float* __restrict__ bs,
                                              float* __restrict__ sums,
                                              float* __restrict__ maxg){
  const int b = blockIdx.x, t = threadIdx.x;
  const float m = bm[b*128 + t];
  float mm = waveRedMax(m);
  __shared__ float r2m[2];
  __shared__ float mgs;
  if ((t & 63) == 0) r2m[t >> 6] = mm;
  __syncthreads();
  if (t == 0) mgs = fmaxf(r2m[0], r2m[1]);
  __syncthreads();
  const float mg = mgs;
  float v = bs[b*128 + t] * __expf(m - mg);
  v = waveRedSum(v);
  __shared__ float r2s[2];
  if ((t & 63) == 0) r2s[t >> 6] = v;
  __syncthreads();
  if (t == 0){ sums[b] = r2s[0] + r2s[1]; maxg[b] = mg; }
}

// ================= K7: out = (exp(L-maxg) @ H) / sums, MFMA split-bf16 ==============
__global__ __launch_bounds__(256) void k7_out(const float* __restrict__ Lr,
                                              const float* __restrict__ Hm,
                                              const float* __restrict__ sums,
                                              const float* __restrict__ maxg,
                                              float* __restrict__ out){
  __shared__ short Ah[2][64*40];
  __shared__ short Al[2][64*40];
  __shared__ short Bh[2][64*40];
  __shared__ short Bl[2][64*40];
  const int fid = blockIdx.x;
  const int b = fid & 7, idx = fid >> 3;
  const int y = idx / 5, x = idx % 5;
  const int m0 = y * 64, c0 = x * 64;
  const int t = threadIdx.x;
  const int lane = t & 63, wv = t >> 6;
  const int wr = wv >> 1, wc = wv & 1;
  const float mx = maxg[b];
  const int srow = t >> 2, kq = (t & 3) * 8;
  const float* Lrow = Lr + (size_t)(b*512 + m0 + srow) * 512 + kq;
  const int tk = t >> 4, tn = t & 15;
  const int k0 = tk * 2, n0 = tn * 4;
  const int gcolB = c0 + n0;
  const bool bok = gcolB < 300;
  float4 ra0, ra1, hb0, hb1;
#define K7_LD(kt) { \
    ra0 = *(const float4*)(Lrow + (kt)); \
    ra1 = *(const float4*)(Lrow + (kt) + 4); \
    const float* hr = Hm + (size_t)(b*512 + (kt) + k0) * 300 + gcolB; \
    hb0 = bok ? *(const float4*)hr : f4z(); \
    hb1 = bok ? *(const float4*)(hr + 300) : f4z(); }
  K7_LD(0)
  f32x4 acc[2][2];
  #pragma unroll
  for (int i = 0; i < 2; i++)
    #pragma unroll
    for (int jj = 0; jj < 2; jj++)
      acc[i][jj] = (f32x4){0.f, 0.f, 0.f, 0.f};
  const int fr = lane & 15;
  const int fg = lane >> 4;
  const int fk = fg * 8;
  int p = 0;
  for (int tile = 0; tile < 16; ++tile){
    {
      float av[8] = {ra0.x, ra0.y, ra0.z, ra0.w, ra1.x, ra1.y, ra1.z, ra1.w};
      short8 vah, val_;
      #pragma unroll
      for (int i = 0; i < 8; i++){
        const float e = __expf(av[i] - mx);
        unsigned short hh = f2bf(e);
        vah[i] = (short)hh;
        val_[i] = (short)f2bf(e - bf2f(hh));
      }
      const int o = srow * 40 + kq;
      *(short8*)&Ah[p][o] = vah;
      *(short8*)&Al[p][o] = val_;
      #pragma unroll
      for (int i = 0; i < 4; i++){
        const float v0 = F4C(hb0, i), v1 = F4C(hb1, i);
        const unsigned short h0 = f2bf(v0), h1 = f2bf(v1);
        const unsigned short l0 = f2bf(v0 - bf2f(h0)), l1 = f2bf(v1 - bf2f(h1));
        const int n = n0 + i;
        const int kbs = (k0 >> 3) ^ (n & 3);
        const int soff = n*40 + kbs*8 + (k0 & 7);
        *(unsigned*)&Bh[p][soff] = (unsigned)h0 | ((unsigned)h1 << 16);
        *(unsigned*)&Bl[p][soff] = (unsigned)l0 | ((unsigned)l1 << 16);
      }
    }
    __syncthreads();
    if (tile < 15) K7_LD((tile + 1) * 32)
    {
      const int a0o = (wr*32      + fr) * 40 + fk;
      const int a1o = (wr*32 + 16 + fr) * 40 + fk;
      const int nb0 = wc*32      + fr;
      const int nb1 = wc*32 + 16 + fr;
      const int b0o = nb0*40 + (fg ^ (nb0 & 3)) * 8;
      const int b1o = nb1*40 + (fg ^ (nb1 & 3)) * 8;
      short8 fAh[2], fAl[2], fBh[2], fBl[2];
      fAh[0] = *(short8*)&Ah[p][a0o]; fAh[1] = *(short8*)&Ah[p][a1o];
      fAl[0] = *(short8*)&Al[p][a0o]; fAl[1] = *(short8*)&Al[p][a1o];
      fBh[0] = *(short8*)&Bh[p][b0o]; fBh[1] = *(short8*)&Bh[p][b1o];
      fBl[0] = *(short8*)&Bl[p][b0o]; fBl[1] = *(short8*)&Bl[p][b1o];
      #pragma unroll
      for (int sm = 0; sm < 2; sm++)
        #pragma unroll
        for (int sn = 0; sn < 2; sn++){
          acc[sm][sn] = __builtin_amdgcn_mfma_f32_16x16x32_bf16(fAh[sm], fBh[sn], acc[sm][sn], 0, 0, 0);
          acc[sm][sn] = __builtin_amdgcn_mfma_f32_16x16x32_bf16(fAh[sm], fBl[sn], acc[sm][sn], 0, 0, 0);
          acc[sm][sn] = __builtin_amdgcn_mfma_f32_16x16x32_bf16(fAl[sm], fBh[sn], acc[sm][sn], 0, 0, 0);
        }
    }
    p ^= 1;
  }
#undef K7_LD
  const float invs = 1.0f / sums[b];
  const int crow = (lane >> 4) * 4;
  const int ccol = lane & 15;
  #pragma unroll
  for (int sn = 0; sn < 2; sn++){
    const int gcol = c0 + wc*32 + sn*16 + ccol;
    if (gcol < 300){
      #pragma unroll
      for (int sm = 0; sm < 2; sm++){
        const int rbase = m0 + wr*32 + sm*16 + crow;
        #pragma unroll
        for (int r = 0; r < 4; r++)
          out[(size_t)(b*512 + rbase + r) * 300 + gcol] = acc[sm][sn][r] * invs;
      }
    }
  }
}

extern "C" void kernel_launch(void* const* d_in, const int* in_sizes, int n_in,
                              void* d_out, int out_size, void* d_ws, size_t ws_size,
                              hipStream_t stream){
  const float* adj  = (const float*)d_in[0];
  const float* feat = (const float*)d_in[1];
  const float* Ww   = (const float*)d_in[2];
  const float* Wb   = (const float*)d_in[3];
  const float* a1w  = (const float*)d_in[4];
  const float* a1b  = (const float*)d_in[5];
  const float* a2w  = (const float*)d_in[6];
  const float* a2b  = (const float*)d_in[7];
  float* out = (float*)d_out;
  char* ws = (char*)d_ws;

  float* H    = (float*)(ws + 0);           // 4,915,200 B
  float* S    = (float*)(ws + 4915200);     // 2,097,152 B
  float* L    = (float*)(ws + 7012352);     // 8,388,608 B
  float* bm   = (float*)(ws + 15400960);    // 4,096 B
  float* bs   = (float*)(ws + 15405056);    // 4,096 B
  float* sums = (float*)(ws + 15409152);    // 32 B
  float* maxg = (float*)(ws + 15409216);    // 32 B

  k1_h     <<<dim3(320),      dim3(256), 0, stream>>>(feat, Ww, Wb, H);
  k2_s     <<<dim3(128),      dim3(256), 0, stream>>>(H, a1w, a1b, S);
  k3_logits<<<dim3(8, 16, 8), dim3(256), 0, stream>>>(S, adj, a2w, a2b, L, bm, bs);
  k6_red   <<<dim3(8),        dim3(128), 0, stream>>>(bm, bs, sums, maxg);
  k7_out   <<<dim3(320),      dim3(256), 0, stream>>>(L, H, sums, maxg, out);
}